// Round 12
// baseline (979.717 us; speedup 1.0000x reference)
//
#include <hip/hip_runtime.h>
#include <cstdint>

#define N_NODES 50000
#define N_EDGES 800000
#define HDIM    128
#define TIE_CAP 44000
#define NITER   2
#define SCAN_B  256
#define EB_CONST 3125            // N_EDGES/256
#define TB_CONST 172             // ceil(TIE_CAP/256)
#define GM_T     344             // ceil(TIE_CAP/128) tie tile blocks
#define COPY_B   1664            // e-copy blocks appended to iter-1 tie launch

typedef __attribute__((ext_vector_type(8))) short bf16x8;
typedef __attribute__((ext_vector_type(4))) float f32x4;

__device__ __forceinline__ uint32_t f2bf(float f) {
    uint32_t u = __builtin_bit_cast(uint32_t, f);
    return (u + 0x7fffu + ((u >> 16) & 1u)) >> 16;   // RNE
}
__device__ __forceinline__ float bf2f(uint32_t b) {
    return __builtin_bit_cast(float, b << 16);
}
__device__ __forceinline__ uint32_t comb2(uint32_t me, uint32_t mn, float g) {
    float a0 = bf2f(me & 0xffffu) + g * bf2f(mn & 0xffffu);
    float a1 = bf2f(me >> 16)     + g * bf2f(mn >> 16);
    return f2bf(a0) | (f2bf(a1) << 16);
}

// ---- LDS tiles: [128 rows][128 bf16] = 256B rows, byte ^= (row&7)<<4 ----

__device__ __forceinline__ void stage_a128(const float* __restrict__ base,
                                           const int* __restrict__ gidx,
                                           int m0, int Mlim, char* tile, int tid)
{
    const int c = tid & 15;
    #pragma unroll
    for (int p = 0; p < 4; ++p) {
        int row = p * 32 + (tid >> 4);
        int ar = m0 + row; if (ar >= Mlim) ar = Mlim - 1;
        long g = gidx ? gidx[ar] : ar;
        const float* s = base + g * HDIM + c * 4;
        float4 v0 = *(const float4*)s;
        float4 v1 = *(const float4*)(s + 64);
        uint2 w0 = make_uint2(f2bf(v0.x) | (f2bf(v0.y) << 16),
                              f2bf(v0.z) | (f2bf(v0.w) << 16));
        uint2 w1 = make_uint2(f2bf(v1.x) | (f2bf(v1.y) << 16),
                              f2bf(v1.z) | (f2bf(v1.w) << 16));
        int sw = (row & 7) << 4;
        *(uint2*)(tile + row * 256 + ((c * 8) ^ sw)) = w0;
        *(uint2*)(tile + row * 256 + ((c * 8 + 128) ^ sw)) = w1;
    }
}

__device__ __forceinline__ void stage_bf128(const uint16_t* __restrict__ base,
                                            const int* __restrict__ gidx,
                                            int m0, int Mlim, char* tile, int tid)
{
    const int c = tid & 15;
    #pragma unroll
    for (int p = 0; p < 4; ++p) {
        int row = p * 32 + (tid >> 4);
        int ar = m0 + row; if (ar >= Mlim) ar = Mlim - 1;
        long g = gidx ? gidx[ar] : ar;
        uint4 v = *(const uint4*)(base + g * HDIM + c * 8);
        *(uint4*)(tile + row * 256 + ((c * 16) ^ ((row & 7) << 4))) = v;
    }
}

__device__ __forceinline__ void stage_b128(const short* __restrict__ BT, int ldk,
                                           int n0, int k0, char* tile, int tid)
{
    const int c = tid & 15;
    #pragma unroll
    for (int p = 0; p < 4; ++p) {
        int n = p * 32 + (tid >> 4);
        uint4 v = *(const uint4*)&BT[(size_t)(n0 + n) * ldk + k0 + c * 8];
        *(uint4*)(tile + n * 256 + ((c * 16) ^ ((n & 7) << 4))) = v;
    }
}

// one K=128 chunk: 8 waves in 2(M)x4(N); wave does 64x32 via 16x16x32 MFMA
__device__ __forceinline__ void mfma128(const char* At, const char* Bt,
                                        int wr, int wc, int lane, f32x4 acc[4][2])
{
    #pragma unroll
    for (int ks = 0; ks < 4; ++ks) {
        int kb = ks * 64 + (lane >> 4) * 16;
        bf16x8 aF[4], bF[2];
        #pragma unroll
        for (int mi = 0; mi < 4; ++mi) {
            int row = wr * 64 + mi * 16 + (lane & 15);
            aF[mi] = *(const bf16x8*)(At + row * 256 + (kb ^ ((row & 7) << 4)));
        }
        #pragma unroll
        for (int ni = 0; ni < 2; ++ni) {
            int n = wc * 32 + ni * 16 + (lane & 15);
            bF[ni] = *(const bf16x8*)(Bt + n * 256 + (kb ^ ((n & 7) << 4)));
        }
        #pragma unroll
        for (int mi = 0; mi < 4; ++mi)
            #pragma unroll
            for (int ni = 0; ni < 2; ++ni)
                acc[mi][ni] = __builtin_amdgcn_mfma_f32_16x16x32_bf16(
                    aF[mi], bF[ni], acc[mi][ni], 0, 0, 0);
    }
}

// -------- fused tie-edge kernel + (iter-1 only) co-scheduled e-copy ---------
// blocks [0,GM_T): tie tiles (read A rows from e_src, write out_e)
// blocks [GM_T, ...): stream-copy NON-tie rows e -> out_e (tie rows are
// written by the tie blocks, so no write-write race)
__global__ __launch_bounds__(512)
void k_tie_fused(const float* __restrict__ e_src, float* __restrict__ out_e,
                 const float* __restrict__ e_orig,
                 const void* __restrict__ tie_raw, const int* __restrict__ counters,
                 const uint16_t* __restrict__ h_bf,
                 const int* __restrict__ tie_list, const int* __restrict__ tie_row,
                 const int* __restrict__ tie_col,
                 const short* __restrict__ BTer1, const short* __restrict__ BTer2,
                 const float* __restrict__ b_er1, const float* __restrict__ b_er2)
{
    const int tid = threadIdx.x;

    if ((int)blockIdx.x >= GM_T) {
        // ---- e-copy of non-tie rows (iter-1 grid only) ----
        int fmt = counters[0];
        const float4* src = (const float4*)e_orig;
        float4* dst = (float4*)out_e;
        for (int i = ((int)blockIdx.x - GM_T) * 512 + tid;
             i < N_EDGES * (HDIM / 4); i += COPY_B * 512) {
            int row = i >> 5;   // 32 float4 per row
            bool t = fmt ? (((const uint8_t*)tie_raw)[row] != 0)
                         : (((const int*)tie_raw)[row] != 0);
            if (!t) dst[i] = src[i];
        }
        return;
    }

    int cnt = counters[1]; if (cnt > TIE_CAP) cnt = TIE_CAP;
    const int m0 = blockIdx.x * 128;
    if (m0 >= cnt) return;

    __shared__ __align__(16) char At[32 * 1024];
    __shared__ __align__(16) char B0[32 * 1024];
    __shared__ __align__(16) char B1[32 * 1024];

    const int lane = tid & 63;
    const int wid = tid >> 6, wr = wid >> 2, wc = wid & 3;

    f32x4 acc0[4][2] = {}, acc1[4][2] = {};
    #pragma unroll 1
    for (int c = 0; c < 3; ++c) {
        if (c == 0) stage_a128(e_src, tie_list, m0, cnt, At, tid);
        else        stage_bf128(h_bf, (c == 1) ? tie_row : tie_col, m0, cnt, At, tid);
        stage_b128(BTer1, 384, 0,   c * 128, B0, tid);
        stage_b128(BTer1, 384, 128, c * 128, B1, tid);
        __syncthreads();
        mfma128(At, B0, wr, wc, lane, acc0);
        mfma128(At, B1, wr, wc, lane, acc1);
        __syncthreads();
    }

    // epilogue1: relu(acc+b) -> bf16 C1 tiles (At = cols 0-127, B0 = 128-255)
    #pragma unroll
    for (int half = 0; half < 2; ++half) {
        char* Ct = half ? B0 : At;
        #pragma unroll
        for (int ni = 0; ni < 2; ++ni) {
            int col = wc * 32 + ni * 16 + (lane & 15);
            float bv = b_er1[half * 128 + col];
            #pragma unroll
            for (int mi = 0; mi < 4; ++mi)
                #pragma unroll
                for (int j = 0; j < 4; ++j) {
                    int rl = wr * 64 + mi * 16 + ((lane >> 4) << 2) + j;
                    float v = fmaxf((half ? acc1 : acc0)[mi][ni][j] + bv, 0.f);
                    *(uint16_t*)(Ct + rl * 256 + ((col * 2) ^ ((rl & 7) << 4))) =
                        (uint16_t)f2bf(v);
                }
        }
    }
    stage_b128(BTer2, 256, 0, 0, B1, tid);
    __syncthreads();
    f32x4 acc2[4][2] = {};
    mfma128(At, B1, wr, wc, lane, acc2);
    __syncthreads();
    stage_b128(BTer2, 256, 0, 128, B1, tid);
    __syncthreads();
    mfma128(B0, B1, wr, wc, lane, acc2);

    // epilogue2: out_e[tie] = e_src[tie] + eref
    int col0 = wc * 32 + (lane & 15);
    float bv0 = b_er2[col0], bv1 = b_er2[col0 + 16];
    #pragma unroll
    for (int mi = 0; mi < 4; ++mi) {
        #pragma unroll
        for (int j = 0; j < 4; ++j) {
            int i = m0 + wr * 64 + mi * 16 + ((lane >> 4) << 2) + j;
            if (i < cnt) {
                int e = tie_list[i];
                #pragma unroll
                for (int ni = 0; ni < 2; ++ni) {
                    int col = col0 + ni * 16;
                    size_t eb = (size_t)e * HDIM + col;
                    out_e[eb] = e_src[eb] + acc2[mi][ni][j] + (ni ? bv1 : bv0);
                }
            }
        }
    }
}

// ---------------- gather: agg + m_edge (tie-CSR), per node ------------------
__global__ __launch_bounds__(256)
void k_gather(const int* __restrict__ row_ptr, const int* __restrict__ csr_row,
              const float* __restrict__ csr_w, const uint16_t* __restrict__ h_bf,
              uint16_t* __restrict__ agg,
              const int* __restrict__ row_ptr2, const int* __restrict__ tcsr,
              const float* __restrict__ out_e, const float* __restrict__ deg_inv,
              uint16_t* __restrict__ m_edge_bf)
{
    int n = blockIdx.x * 4 + (threadIdx.x >> 6);
    if (n >= N_NODES) return;
    int lane = threadIdx.x & 63;

    int s = row_ptr[n], t = row_ptr[n + 1];
    float a0 = 0.f, a1 = 0.f;
    for (int j = s; j < t; ++j) {
        int r = csr_row[j];
        float w = csr_w[j];
        uint32_t v = *(const uint32_t*)(h_bf + (size_t)r * HDIM + lane * 2);
        a0 += w * bf2f(v & 0xffffu);
        a1 += w * bf2f(v >> 16);
    }
    *(uint32_t*)(agg + (size_t)n * HDIM + lane * 2) = f2bf(a0) | (f2bf(a1) << 16);

    int s2 = row_ptr2[n], t2 = row_ptr2[n + 1];
    float b0 = 0.f, b1 = 0.f;
    for (int j = s2; j < t2; ++j) {
        int e = tcsr[j];
        float2 v = *(const float2*)(out_e + (size_t)e * HDIM + lane * 2);
        b0 += v.x; b1 += v.y;
    }
    float di = deg_inv[n];
    *(uint32_t*)(m_edge_bf + (size_t)n * HDIM + lane * 2) =
        f2bf(b0 * di) | (f2bf(b1 * di) << 16);
}

// ---------------- fused node kernel (bf16 m_edge; GRU ping-pong B) ----------
__global__ __launch_bounds__(512)
void k_node_mega(const uint16_t* __restrict__ m_edge_bf,
                 const uint16_t* __restrict__ agg,
                 float* __restrict__ out_h, uint16_t* __restrict__ h_bf,
                 const float* __restrict__ cpl_cnt, const float* __restrict__ sumw,
                 const short* __restrict__ BTnn, const float* __restrict__ b_nn,
                 const short* __restrict__ BTg1, const float* __restrict__ b_g1,
                 const float* __restrict__ Wg2, const float* __restrict__ b_g2,
                 const short* __restrict__ BTcomb,
                 const short* __restrict__ BTihn, const short* __restrict__ BThhn,
                 const float* __restrict__ b_ih, const float* __restrict__ b_hh)
{
    const int m0 = blockIdx.x * 128;
    __shared__ __align__(16) char Tme[32 * 1024];   // m_edge tile; B buf in GRU
    __shared__ __align__(16) char Tmn[32 * 1024];   // agg -> m_node -> M
    __shared__ __align__(16) char Th [32 * 1024];
    __shared__ __align__(16) char Bt [32 * 1024];
    __shared__ float g_red[4][128];
    __shared__ float g_fin[128];
    __shared__ float sw_s[128];

    const int tid = threadIdx.x, lane = tid & 63;
    const int wid = tid >> 6, wr = wid >> 2, wc = wid & 3;

    stage_bf128(m_edge_bf, nullptr, m0, N_NODES, Tme, tid);
    stage_bf128(agg,       nullptr, m0, N_NODES, Tmn, tid);
    stage_bf128(h_bf,      nullptr, m0, N_NODES, Th,  tid);
    stage_b128(BTnn, 128, 0, 0, Bt, tid);
    if (tid < 128) {
        int n = m0 + tid; if (n >= N_NODES) n = N_NODES - 1;
        sw_s[tid] = sumw[n];
    }
    __syncthreads();

    // ---- phase 0: m_node = agg @ W_nn + sumw*b_nn  -> bf16 into Tmn ----
    {
        f32x4 accM[4][2] = {};
        mfma128(Tmn, Bt, wr, wc, lane, accM);
        __syncthreads();
        #pragma unroll
        for (int ni = 0; ni < 2; ++ni) {
            int col = wc * 32 + ni * 16 + (lane & 15);
            float bv = b_nn[col];
            #pragma unroll
            for (int mi = 0; mi < 4; ++mi)
                #pragma unroll
                for (int j = 0; j < 4; ++j) {
                    int rl = wr * 64 + mi * 16 + ((lane >> 4) << 2) + j;
                    float v = accM[mi][ni][j] + sw_s[rl] * bv;
                    *(uint16_t*)(Tmn + rl * 256 + ((col * 2) ^ ((rl & 7) << 4))) =
                        (uint16_t)f2bf(v);
                }
        }
        __syncthreads();
    }

    // ---- gate GEMM: [me|mn|h](K=384) @ W_g1 ----
    f32x4 accG[4][2] = {};
    #pragma unroll 1
    for (int c = 0; c < 3; ++c) {
        const char* Ac = (c == 0) ? Tme : (c == 1) ? Tmn : Th;
        stage_b128(BTg1, 384, 0, c * 128, Bt, tid);
        __syncthreads();
        mfma128(Ac, Bt, wr, wc, lane, accG);
        __syncthreads();
    }
    {
        float bg[2], wg[2];
        #pragma unroll
        for (int ni = 0; ni < 2; ++ni) {
            int col = wc * 32 + ni * 16 + (lane & 15);
            bg[ni] = b_g1[col]; wg[ni] = Wg2[col];
        }
        #pragma unroll
        for (int mi = 0; mi < 4; ++mi)
            #pragma unroll
            for (int j = 0; j < 4; ++j) {
                float p = fmaxf(accG[mi][0][j] + bg[0], 0.f) * wg[0]
                        + fmaxf(accG[mi][1][j] + bg[1], 0.f) * wg[1];
                #pragma unroll
                for (int o = 8; o; o >>= 1) p += __shfl_xor(p, o);
                if ((lane & 15) == 0)
                    g_red[wc][wr * 64 + mi * 16 + ((lane >> 4) << 2) + j] = p;
            }
    }
    __syncthreads();
    if (tid < 128) {
        float t = g_red[0][tid] + g_red[1][tid] + g_red[2][tid] + g_red[3][tid]
                + b_g2[0];
        g_fin[tid] = 1.f / (1.f + __expf(-t));
    }
    __syncthreads();

    // M = me + g*mn (in place of Tmn); C0 staged alongside
    stage_b128(BTcomb, 256, 0, 0, Bt, tid);
    {
        const int c = tid & 15;
        #pragma unroll
        for (int p = 0; p < 4; ++p) {
            int row = p * 32 + (tid >> 4);
            float g = g_fin[row];
            int sw = (row & 7) << 4;
            #pragma unroll
            for (int hh = 0; hh < 2; ++hh) {
                int off = (c * 8 + hh * 128) ^ sw;
                uint2 me2 = *(uint2*)(Tme + row * 256 + off);
                uint2 mn2 = *(uint2*)(Tmn + row * 256 + off);
                *(uint2*)(Tmn + row * 256 + off) =
                    make_uint2(comb2(me2.x, mn2.x, g), comb2(me2.y, mn2.y, g));
            }
        }
    }
    __syncthreads();    // covers M-combine + C0 stage; Tme now DEAD -> B buffer

    // ---- GRU phases: ping-pong B between Bt and Tme ----
    f32x4 aR[4][2] = {}, aZ[4][2] = {}, aGI[4][2] = {}, aGH[4][2] = {};
    stage_b128(BTcomb, 256, 0, 128, Tme, tid);
    mfma128(Tmn, Bt, wr, wc, lane, aR);   __syncthreads();
    stage_b128(BTcomb, 256, 128, 0, Bt, tid);
    mfma128(Th, Tme, wr, wc, lane, aR);   __syncthreads();
    stage_b128(BTcomb, 256, 128, 128, Tme, tid);
    mfma128(Tmn, Bt, wr, wc, lane, aZ);   __syncthreads();
    stage_b128(BTihn, 128, 0, 0, Bt, tid);
    mfma128(Th, Tme, wr, wc, lane, aZ);   __syncthreads();
    stage_b128(BThhn, 128, 0, 0, Tme, tid);
    mfma128(Tmn, Bt, wr, wc, lane, aGI);  __syncthreads();
    mfma128(Th, Tme, wr, wc, lane, aGH);

    // ---- GRU epilogue (masked); maintains h_bf shadow ----
    #pragma unroll
    for (int ni = 0; ni < 2; ++ni) {
        int col = wc * 32 + ni * 16 + (lane & 15);
        float br  = b_ih[col] + b_hh[col];
        float bz  = b_ih[128 + col] + b_hh[128 + col];
        float bin = b_ih[256 + col], bhn = b_hh[256 + col];
        #pragma unroll
        for (int mi = 0; mi < 4; ++mi)
            #pragma unroll
            for (int j = 0; j < 4; ++j) {
                int node = m0 + wr * 64 + mi * 16 + ((lane >> 4) << 2) + j;
                if (node < N_NODES && cpl_cnt[node] > 0.f) {
                    float r = 1.f / (1.f + __expf(-(aR[mi][ni][j] + br)));
                    float z = 1.f / (1.f + __expf(-(aZ[mi][ni][j] + bz)));
                    float nn = tanhf(aGI[mi][ni][j] + bin + r * (aGH[mi][ni][j] + bhn));
                    size_t hb = (size_t)node * HDIM + col;
                    float hv = out_h[hb];
                    float hn = (1.f - z) * nn + z * hv;
                    out_h[hb] = hn;
                    h_bf[hb] = (uint16_t)f2bf(hn);
                }
            }
    }
}

// ---------------- k_init: block-partitioned prep (NO e-copy now) ------------
// [0,256): h->out_h+h_bf  [256,320): node zero  [320,448): weights  448: detect
#define INIT_BLOCKS 449

__global__ __launch_bounds__(256)
void k_init(const float* __restrict__ h, float* __restrict__ out_h,
            uint16_t* __restrict__ h_bf,
            float* __restrict__ cpl_cnt, float* __restrict__ w_den,
            int* __restrict__ hist, int* __restrict__ counters,
            const uint8_t* __restrict__ tie_raw,
            const float* __restrict__ W_er1, const float* __restrict__ W_er2,
            const float* __restrict__ W_nn, const float* __restrict__ W_g1,
            const float* __restrict__ W_ih, const float* __restrict__ W_hh,
            short* __restrict__ BTer1, short* __restrict__ BTer2,
            short* __restrict__ BTnn, short* __restrict__ BTg1,
            short* __restrict__ BTcomb, short* __restrict__ BTihn,
            short* __restrict__ BThhn)
{
    const int b = blockIdx.x, t = threadIdx.x;
    if (b < 256) {
        for (int i = b * 256 + t; i < N_NODES * HDIM / 4; i += 256 * 256) {
            float4 v = ((const float4*)h)[i];
            ((float4*)out_h)[i] = v;
            *(uint2*)(h_bf + (size_t)i * 4) =
                make_uint2(f2bf(v.x) | (f2bf(v.y) << 16),
                           f2bf(v.z) | (f2bf(v.w) << 16));
        }
    } else if (b < 320) {
        for (int i = (b - 256) * 256 + t; i < N_NODES; i += 64 * 256) {
            cpl_cnt[i] = 0.f; w_den[i] = 0.f; hist[i] = 0;
        }
    } else if (b < 448) {
        for (int i = (b - 320) * 256 + t; i < 384 * 256; i += 128 * 256) {
            {   int n = i / 384, k = i % 384;
                BTer1[i] = (short)f2bf(W_er1[(size_t)k * 256 + n]); }
            if (i < 128 * 256) {
                int n = i / 256, k = i % 256;
                BTer2[i] = (short)f2bf(W_er2[(size_t)k * 128 + n]); }
            if (i < 128 * 128) {
                int n = i / 128, k = i % 128;
                BTnn[i] = (short)f2bf(W_nn[(size_t)k * 128 + n]); }
            if (i < 128 * 384) {
                int n = i / 384, k = i % 384;
                BTg1[i] = (short)f2bf(W_g1[(size_t)k * 128 + n]); }
            if (i < 256 * 256) {
                int n = i >> 8, k = i & 255;
                float v = (k < 128) ? W_ih[n * 128 + k] : W_hh[n * 128 + (k - 128)];
                BTcomb[i] = (short)f2bf(v); }
            if (i < 128 * 128) {
                BTihn[i] = (short)f2bf(W_ih[256 * 128 + i]);
                BThhn[i] = (short)f2bf(W_hh[256 * 128 + i]); }
        }
    } else {
        if (t < 64) {
            int c = 0;
            for (int k = t; k < 4096; k += 64)
                if ((k & 3) && tie_raw[k]) c = 1;
            unsigned long long m = __ballot(c != 0);
            if (t == 0) {
                counters[0] = (m != 0ull) ? 1 : 0;
                counters[1] = 0; counters[2] = 0; counters[3] = 0;
            }
        }
    }
}

// ---------------- tie classification (wave-aggregated compaction) -----------
__global__ __launch_bounds__(256)
void k_tie(const void* __restrict__ tie_raw, const int* __restrict__ counters,
           const int* __restrict__ ei, float* __restrict__ cpl_cnt,
           int* __restrict__ tie_cnt, int* __restrict__ tie_list,
           int* __restrict__ tie_row, int* __restrict__ tie_col)
{
    int e = blockIdx.x * 256 + threadIdx.x;
    int fmt = counters[0];
    bool t = false; int r = 0, c = 0;
    if (e < N_EDGES)
        t = fmt ? (((const uint8_t*)tie_raw)[e] != 0)
                : (((const int*)tie_raw)[e] != 0);
    if (t) {
        r = ei[e]; c = ei[N_EDGES + e];
        atomicAdd(&cpl_cnt[r], 1.f);
        atomicAdd(&cpl_cnt[c], 1.f);
    }
    unsigned long long m = __ballot(t);
    if (m == 0ull) return;
    int lane = threadIdx.x & 63;
    int first = __ffsll((unsigned long long)m) - 1;
    int base = 0;
    if (lane == first) base = atomicAdd(tie_cnt, __popcll(m));
    base = __shfl(base, first);
    if (t) {
        int idx = base + __popcll(m & ((1ull << lane) - 1ull));
        if (idx < TIE_CAP) { tie_list[idx] = e; tie_row[idx] = r; tie_col[idx] = c; }
    }
}

__global__ __launch_bounds__(256)
void k_w(const void* __restrict__ tie_raw, const int* __restrict__ counters,
         const int* __restrict__ ei, const float* __restrict__ attr,
         const float* __restrict__ cpl_cnt, float* __restrict__ w_den,
         float* __restrict__ w_arr, int* __restrict__ hist)
{
    int e = blockIdx.x * 256 + threadIdx.x;
    if (e >= N_EDGES) return;
    int fmt = counters[0];
    bool t = fmt ? (((const uint8_t*)tie_raw)[e] != 0)
                 : (((const int*)tie_raw)[e] != 0);
    float w = 0.f;
    if (!t) {
        int c = ei[N_EDGES + e];
        if (cpl_cnt[c] > 0.f) {
            float X = fabsf(attr[(size_t)e * 10 + 1]);
            w = 1.f / sqrtf(X * X + 1e-6f);
            atomicAdd(&w_den[c], w);
            atomicAdd(&hist[c], 1);
        }
    }
    w_arr[e] = w;
}

// ---------------- dual CSR build ----------------
__global__ __launch_bounds__(SCAN_B)
void k_scan1(const int* __restrict__ hist, const float* __restrict__ cpl_cnt,
             int* __restrict__ excl, int* __restrict__ bsum,
             int* __restrict__ excl2, int* __restrict__ bsum2)
{
    __shared__ int s[SCAN_B];
    int t = threadIdx.x;
    int i = blockIdx.x * SCAN_B + t;
    int v = (i < N_NODES) ? hist[i] : 0;
    s[t] = v;
    __syncthreads();
    for (int o = 1; o < SCAN_B; o <<= 1) {
        int u = (t >= o) ? s[t - o] : 0;
        __syncthreads();
        s[t] += u;
        __syncthreads();
    }
    if (i < N_NODES) excl[i] = s[t] - v;
    if (t == SCAN_B - 1) bsum[blockIdx.x] = s[t];
    __syncthreads();
    int v2 = (i < N_NODES) ? (int)cpl_cnt[i] : 0;
    s[t] = v2;
    __syncthreads();
    for (int o = 1; o < SCAN_B; o <<= 1) {
        int u = (t >= o) ? s[t - o] : 0;
        __syncthreads();
        s[t] += u;
        __syncthreads();
    }
    if (i < N_NODES) excl2[i] = s[t] - v2;
    if (t == SCAN_B - 1) bsum2[blockIdx.x] = s[t];
}

__global__ void k_scan2(int* __restrict__ bsum, int* __restrict__ bsum2,
                        int* __restrict__ counters)
{
    const int NB = (N_NODES + SCAN_B - 1) / SCAN_B;
    if (threadIdx.x == 0) {
        int run = 0;
        for (int b = 0; b < NB; ++b) { int x = bsum[b]; bsum[b] = run; run += x; }
        counters[2] = run;
        int run2 = 0;
        for (int b = 0; b < NB; ++b) { int x = bsum2[b]; bsum2[b] = run2; run2 += x; }
        counters[3] = run2;
    }
}

__global__ __launch_bounds__(256)
void k_scan3(const int* __restrict__ excl, const int* __restrict__ bsum,
             const int* __restrict__ excl2, const int* __restrict__ bsum2,
             int* __restrict__ row_ptr, int* __restrict__ cursor,
             int* __restrict__ row_ptr2, int* __restrict__ cursor2,
             const int* __restrict__ counters,
             const float* __restrict__ cpl_cnt, const float* __restrict__ w_den,
             float* __restrict__ deg_inv, float* __restrict__ sumw)
{
    int i = blockIdx.x * 256 + threadIdx.x;
    if (i < N_NODES) {
        int v = excl[i] + bsum[i >> 8];
        row_ptr[i] = v;  cursor[i] = v;
        int v2 = excl2[i] + bsum2[i >> 8];
        row_ptr2[i] = v2; cursor2[i] = v2;
        deg_inv[i] = 1.f / fmaxf(cpl_cnt[i], 1.f);
        float wd = w_den[i];
        sumw[i] = wd / (wd + 1e-6f);
    }
    if (i == N_NODES) {
        row_ptr[N_NODES] = counters[2];
        row_ptr2[N_NODES] = counters[3];
    }
}

__global__ __launch_bounds__(256)
void k_fill(const int* __restrict__ ei, const float* __restrict__ w_arr,
            const float* __restrict__ w_den, int* __restrict__ cursor,
            int* __restrict__ csr_row, float* __restrict__ csr_w,
            const int* __restrict__ counters, const int* __restrict__ tie_list,
            const int* __restrict__ tie_row, const int* __restrict__ tie_col,
            int* __restrict__ cursor2, int* __restrict__ tcsr)
{
    int b = blockIdx.x;
    if (b < EB_CONST) {
        int e = b * 256 + threadIdx.x;
        if (e >= N_EDGES) return;
        float w = w_arr[e];
        if (w == 0.f) return;
        int c = ei[N_EDGES + e];
        int pos = atomicAdd(&cursor[c], 1);
        csr_row[pos] = ei[e];
        csr_w[pos] = w / (w_den[c] + 1e-6f);
    } else {
        int i = (b - EB_CONST) * 256 + threadIdx.x;
        int cnt = counters[1]; if (cnt > TIE_CAP) cnt = TIE_CAP;
        if (i < cnt) {
            int e = tie_list[i];
            int p1 = atomicAdd(&cursor2[tie_row[i]], 1); tcsr[p1] = e;
            int p2 = atomicAdd(&cursor2[tie_col[i]], 1); tcsr[p2] = e;
        }
    }
}

// ---------------- launch ----------------
extern "C" void kernel_launch(void* const* d_in, const int* in_sizes, int n_in,
                              void* d_out, int out_size, void* d_ws, size_t ws_size,
                              hipStream_t stream)
{
    const float* h     = (const float*)d_in[0];
    const float* e     = (const float*)d_in[1];
    const float* attr  = (const float*)d_in[2];
    const float* W_er1 = (const float*)d_in[3];
    const float* b_er1 = (const float*)d_in[4];
    const float* W_er2 = (const float*)d_in[5];
    const float* b_er2 = (const float*)d_in[6];
    const float* W_ih  = (const float*)d_in[7];
    const float* W_hh  = (const float*)d_in[8];
    const float* b_ih  = (const float*)d_in[9];
    const float* b_hh  = (const float*)d_in[10];
    const float* W_nn  = (const float*)d_in[11];
    const float* b_nn  = (const float*)d_in[12];
    const float* W_g1  = (const float*)d_in[13];
    const float* b_g1  = (const float*)d_in[14];
    const float* W_g2  = (const float*)d_in[15];
    const float* b_g2  = (const float*)d_in[16];
    const int*   ei    = (const int*)d_in[17];
    const void*  tie_raw = d_in[18];

    float* out_h = (float*)d_out;
    float* out_e = out_h + (size_t)N_NODES * HDIM;

    char* ws = (char*)d_ws;
    size_t off = 0;
    auto alloc = [&](size_t bytes) -> void* {
        void* p = ws + off;
        off = (off + bytes + 255) & ~(size_t)255;
        return p;
    };
    float* cpl_cnt = (float*)alloc((size_t)N_NODES * 4);
    float* w_den   = (float*)alloc((size_t)N_NODES * 4);
    int*   hist    = (int*)  alloc((size_t)N_NODES * 4);
    int*   counters= (int*)  alloc(256);  // [0]=fmt [1]=tie_cnt [2]=csr [3]=tcsr
    float* deg_inv = (float*)alloc((size_t)N_NODES * 4);
    float* sumw    = (float*)alloc((size_t)N_NODES * 4);
    float* w_arr   = (float*)alloc((size_t)N_EDGES * 4);
    int* tie_list  = (int*)alloc((size_t)TIE_CAP * 4);
    int* tie_row   = (int*)alloc((size_t)TIE_CAP * 4);
    int* tie_col   = (int*)alloc((size_t)TIE_CAP * 4);
    short* BTer1   = (short*)alloc((size_t)256 * 384 * 2);
    short* BTer2   = (short*)alloc((size_t)128 * 256 * 2);
    short* BTnn    = (short*)alloc((size_t)128 * 128 * 2);
    short* BTg1    = (short*)alloc((size_t)128 * 384 * 2);
    short* BTcomb  = (short*)alloc((size_t)256 * 256 * 2);
    short* BTihn   = (short*)alloc((size_t)128 * 128 * 2);
    short* BThhn   = (short*)alloc((size_t)128 * 128 * 2);
    uint16_t* h_bf = (uint16_t*)alloc((size_t)N_NODES * HDIM * 2);
    uint16_t* agg  = (uint16_t*)alloc((size_t)N_NODES * HDIM * 2);
    uint16_t* m_edge_bf = (uint16_t*)alloc((size_t)N_NODES * HDIM * 2);
    int* excl      = (int*)alloc((size_t)N_NODES * 4);
    int* excl2     = (int*)alloc((size_t)N_NODES * 4);
    int* bsum      = (int*)alloc(256 * 4);
    int* bsum2     = (int*)alloc(256 * 4);
    int* row_ptr   = (int*)alloc((size_t)(N_NODES + 1) * 4);
    int* row_ptr2  = (int*)alloc((size_t)(N_NODES + 1) * 4);
    int* cursor    = (int*)alloc((size_t)N_NODES * 4);
    int* cursor2   = (int*)alloc((size_t)N_NODES * 4);
    int* csr_row   = (int*)alloc((size_t)N_EDGES * 4);
    float* csr_w   = (float*)alloc((size_t)N_EDGES * 4);
    int* tcsr      = (int*)alloc((size_t)2 * TIE_CAP * 4);
    if (off > ws_size) return;

    const int GM_N = (N_NODES + 127) / 128;          // 391
    const int NB   = (N_NODES + SCAN_B - 1) / SCAN_B;

    k_init<<<INIT_BLOCKS, 256, 0, stream>>>(
        h, out_h, h_bf, cpl_cnt, w_den, hist, counters,
        (const uint8_t*)tie_raw,
        W_er1, W_er2, W_nn, W_g1, W_ih, W_hh,
        BTer1, BTer2, BTnn, BTg1, BTcomb, BTihn, BThhn);
    k_tie<<<EB_CONST, 256, 0, stream>>>(tie_raw, counters, ei, cpl_cnt,
                                        counters + 1, tie_list, tie_row, tie_col);
    k_w<<<EB_CONST, 256, 0, stream>>>(tie_raw, counters, ei, attr, cpl_cnt,
                                      w_den, w_arr, hist);
    k_scan1<<<NB, SCAN_B, 0, stream>>>(hist, cpl_cnt, excl, bsum, excl2, bsum2);
    k_scan2<<<1, 64, 0, stream>>>(bsum, bsum2, counters);
    k_scan3<<<(N_NODES + 256) / 256, 256, 0, stream>>>(
        excl, bsum, excl2, bsum2, row_ptr, cursor, row_ptr2, cursor2,
        counters, cpl_cnt, w_den, deg_inv, sumw);
    k_fill<<<EB_CONST + TB_CONST, 256, 0, stream>>>(
        ei, w_arr, w_den, cursor, csr_row, csr_w,
        counters, tie_list, tie_row, tie_col, cursor2, tcsr);

    for (int it = 0; it < NITER; ++it) {
        const float* e_src = (it == 0) ? e : out_e;
        int grid = (it == 0) ? (GM_T + COPY_B) : GM_T;   // copy rides iter-1
        k_tie_fused<<<grid, 512, 0, stream>>>(
            e_src, out_e, e, tie_raw, counters, h_bf,
            tie_list, tie_row, tie_col,
            BTer1, BTer2, b_er1, b_er2);
        k_gather<<<(N_NODES + 3) / 4, 256, 0, stream>>>(
            row_ptr, csr_row, csr_w, h_bf, agg,
            row_ptr2, tcsr, out_e, deg_inv, m_edge_bf);
        k_node_mega<<<GM_N, 512, 0, stream>>>(
            m_edge_bf, agg, out_h, h_bf, cpl_cnt, sumw,
            BTnn, b_nn, BTg1, b_g1, W_g2, b_g2,
            BTcomb, BTihn, BThhn, b_ih, b_hh);
    }
}

// Round 13
// 975.031 us; speedup vs baseline: 1.0048x; 1.0048x over previous
//
#include <hip/hip_runtime.h>
#include <cstdint>

#define N_NODES 50000
#define N_EDGES 800000
#define HDIM    128
#define TIE_CAP 44000
#define NITER   2
#define SCAN_B  256
#define EB_CONST 3125            // N_EDGES/256
#define TB_CONST 172             // ceil(TIE_CAP/256)
#define GM_T     344             // ceil(TIE_CAP/128) tie tile blocks
#define TOTQ     (N_EDGES * (HDIM / 4))   // 25.6M float4 in e
#define CPB      555             // copy blocks appended per preproc kernel
#define CCHUNK   ((TOTQ + 2) / 3)

typedef __attribute__((ext_vector_type(8))) short bf16x8;
typedef __attribute__((ext_vector_type(4))) float f32x4;

__device__ __forceinline__ uint32_t f2bf(float f) {
    uint32_t u = __builtin_bit_cast(uint32_t, f);
    return (u + 0x7fffu + ((u >> 16) & 1u)) >> 16;   // RNE
}
__device__ __forceinline__ float bf2f(uint32_t b) {
    return __builtin_bit_cast(float, b << 16);
}
__device__ __forceinline__ uint32_t comb2(uint32_t me, uint32_t mn, float g) {
    float a0 = bf2f(me & 0xffffu) + g * bf2f(mn & 0xffffu);
    float a1 = bf2f(me >> 16)     + g * bf2f(mn >> 16);
    return f2bf(a0) | (f2bf(a1) << 16);
}

// copy one third of e -> out_e, skipping tie rows (tie rows are written by
// tie_fused, so skipping avoids the write-write race). No LDS -> full occupancy.
__device__ __forceinline__ void copy_seg(const float* __restrict__ e,
                                         float* __restrict__ out_e,
                                         const void* __restrict__ tie_raw, int fmt,
                                         int cb, int tid, int seg)
{
    int start = seg * CCHUNK;
    int end = start + CCHUNK; if (end > TOTQ) end = TOTQ;
    const float4* src = (const float4*)e;
    float4* dst = (float4*)out_e;
    for (int i = start + cb * 256 + tid; i < end; i += CPB * 256) {
        int row = i >> 5;   // 32 float4 per row
        bool t = fmt ? (((const uint8_t*)tie_raw)[row] != 0)
                     : (((const int*)tie_raw)[row] != 0);
        if (!t) dst[i] = src[i];
    }
}

// ---- LDS tiles: [128 rows][128 bf16] = 256B rows, byte ^= (row&7)<<4 ----

__device__ __forceinline__ void stage_a128(const float* __restrict__ base,
                                           const int* __restrict__ gidx,
                                           int m0, int Mlim, char* tile, int tid)
{
    const int c = tid & 15;
    #pragma unroll
    for (int p = 0; p < 4; ++p) {
        int row = p * 32 + (tid >> 4);
        int ar = m0 + row; if (ar >= Mlim) ar = Mlim - 1;
        long g = gidx ? gidx[ar] : ar;
        const float* s = base + g * HDIM + c * 4;
        float4 v0 = *(const float4*)s;
        float4 v1 = *(const float4*)(s + 64);
        uint2 w0 = make_uint2(f2bf(v0.x) | (f2bf(v0.y) << 16),
                              f2bf(v0.z) | (f2bf(v0.w) << 16));
        uint2 w1 = make_uint2(f2bf(v1.x) | (f2bf(v1.y) << 16),
                              f2bf(v1.z) | (f2bf(v1.w) << 16));
        int sw = (row & 7) << 4;
        *(uint2*)(tile + row * 256 + ((c * 8) ^ sw)) = w0;
        *(uint2*)(tile + row * 256 + ((c * 8 + 128) ^ sw)) = w1;
    }
}

__device__ __forceinline__ void stage_bf128(const uint16_t* __restrict__ base,
                                            const int* __restrict__ gidx,
                                            int m0, int Mlim, char* tile, int tid)
{
    const int c = tid & 15;
    #pragma unroll
    for (int p = 0; p < 4; ++p) {
        int row = p * 32 + (tid >> 4);
        int ar = m0 + row; if (ar >= Mlim) ar = Mlim - 1;
        long g = gidx ? gidx[ar] : ar;
        uint4 v = *(const uint4*)(base + g * HDIM + c * 8);
        *(uint4*)(tile + row * 256 + ((c * 16) ^ ((row & 7) << 4))) = v;
    }
}

__device__ __forceinline__ void stage_b128(const short* __restrict__ BT, int ldk,
                                           int n0, int k0, char* tile, int tid)
{
    const int c = tid & 15;
    #pragma unroll
    for (int p = 0; p < 4; ++p) {
        int n = p * 32 + (tid >> 4);
        uint4 v = *(const uint4*)&BT[(size_t)(n0 + n) * ldk + k0 + c * 8];
        *(uint4*)(tile + n * 256 + ((c * 16) ^ ((n & 7) << 4))) = v;
    }
}

// one K=128 chunk: 8 waves in 2(M)x4(N); wave does 64x32 via 16x16x32 MFMA
__device__ __forceinline__ void mfma128(const char* At, const char* Bt,
                                        int wr, int wc, int lane, f32x4 acc[4][2])
{
    #pragma unroll
    for (int ks = 0; ks < 4; ++ks) {
        int kb = ks * 64 + (lane >> 4) * 16;
        bf16x8 aF[4], bF[2];
        #pragma unroll
        for (int mi = 0; mi < 4; ++mi) {
            int row = wr * 64 + mi * 16 + (lane & 15);
            aF[mi] = *(const bf16x8*)(At + row * 256 + (kb ^ ((row & 7) << 4)));
        }
        #pragma unroll
        for (int ni = 0; ni < 2; ++ni) {
            int n = wc * 32 + ni * 16 + (lane & 15);
            bF[ni] = *(const bf16x8*)(Bt + n * 256 + (kb ^ ((n & 7) << 4)));
        }
        #pragma unroll
        for (int mi = 0; mi < 4; ++mi)
            #pragma unroll
            for (int ni = 0; ni < 2; ++ni)
                acc[mi][ni] = __builtin_amdgcn_mfma_f32_16x16x32_bf16(
                    aF[mi], bF[ni], acc[mi][ni], 0, 0, 0);
    }
}

// ---------------- fused tie-edge kernel (champion R11 form) -----------------
__global__ __launch_bounds__(512)
void k_tie_fused(const float* __restrict__ e_src, float* __restrict__ out_e,
                 const int* __restrict__ counters,
                 const uint16_t* __restrict__ h_bf,
                 const int* __restrict__ tie_list, const int* __restrict__ tie_row,
                 const int* __restrict__ tie_col,
                 const short* __restrict__ BTer1, const short* __restrict__ BTer2,
                 const float* __restrict__ b_er1, const float* __restrict__ b_er2)
{
    int cnt = counters[1]; if (cnt > TIE_CAP) cnt = TIE_CAP;
    const int m0 = blockIdx.x * 128;
    if (m0 >= cnt) return;

    __shared__ __align__(16) char At[32 * 1024];
    __shared__ __align__(16) char B0[32 * 1024];
    __shared__ __align__(16) char B1[32 * 1024];

    const int tid = threadIdx.x, lane = tid & 63;
    const int wid = tid >> 6, wr = wid >> 2, wc = wid & 3;

    f32x4 acc0[4][2] = {}, acc1[4][2] = {};
    #pragma unroll 1
    for (int c = 0; c < 3; ++c) {
        if (c == 0) stage_a128(e_src, tie_list, m0, cnt, At, tid);
        else        stage_bf128(h_bf, (c == 1) ? tie_row : tie_col, m0, cnt, At, tid);
        stage_b128(BTer1, 384, 0,   c * 128, B0, tid);
        stage_b128(BTer1, 384, 128, c * 128, B1, tid);
        __syncthreads();
        mfma128(At, B0, wr, wc, lane, acc0);
        mfma128(At, B1, wr, wc, lane, acc1);
        __syncthreads();
    }

    // epilogue1: relu(acc+b) -> bf16 C1 tiles (At = cols 0-127, B0 = 128-255)
    #pragma unroll
    for (int half = 0; half < 2; ++half) {
        char* Ct = half ? B0 : At;
        #pragma unroll
        for (int ni = 0; ni < 2; ++ni) {
            int col = wc * 32 + ni * 16 + (lane & 15);
            float bv = b_er1[half * 128 + col];
            #pragma unroll
            for (int mi = 0; mi < 4; ++mi)
                #pragma unroll
                for (int j = 0; j < 4; ++j) {
                    int rl = wr * 64 + mi * 16 + ((lane >> 4) << 2) + j;
                    float v = fmaxf((half ? acc1 : acc0)[mi][ni][j] + bv, 0.f);
                    *(uint16_t*)(Ct + rl * 256 + ((col * 2) ^ ((rl & 7) << 4))) =
                        (uint16_t)f2bf(v);
                }
        }
    }
    stage_b128(BTer2, 256, 0, 0, B1, tid);
    __syncthreads();
    f32x4 acc2[4][2] = {};
    mfma128(At, B1, wr, wc, lane, acc2);
    __syncthreads();
    stage_b128(BTer2, 256, 0, 128, B1, tid);
    __syncthreads();
    mfma128(B0, B1, wr, wc, lane, acc2);

    // epilogue2: out_e[tie] = e_src[tie] + eref
    int col0 = wc * 32 + (lane & 15);
    float bv0 = b_er2[col0], bv1 = b_er2[col0 + 16];
    #pragma unroll
    for (int mi = 0; mi < 4; ++mi) {
        #pragma unroll
        for (int j = 0; j < 4; ++j) {
            int i = m0 + wr * 64 + mi * 16 + ((lane >> 4) << 2) + j;
            if (i < cnt) {
                int e = tie_list[i];
                #pragma unroll
                for (int ni = 0; ni < 2; ++ni) {
                    int col = col0 + ni * 16;
                    size_t eb = (size_t)e * HDIM + col;
                    out_e[eb] = e_src[eb] + acc2[mi][ni][j] + (ni ? bv1 : bv0);
                }
            }
        }
    }
}

// ---------------- gather: agg + m_edge (tie-CSR), per node ------------------
__global__ __launch_bounds__(256)
void k_gather(const int* __restrict__ row_ptr, const int* __restrict__ csr_row,
              const float* __restrict__ csr_w, const uint16_t* __restrict__ h_bf,
              uint16_t* __restrict__ agg,
              const int* __restrict__ row_ptr2, const int* __restrict__ tcsr,
              const float* __restrict__ out_e, const float* __restrict__ deg_inv,
              uint16_t* __restrict__ m_edge_bf)
{
    int n = blockIdx.x * 4 + (threadIdx.x >> 6);
    if (n >= N_NODES) return;
    int lane = threadIdx.x & 63;

    int s = row_ptr[n], t = row_ptr[n + 1];
    float a0 = 0.f, a1 = 0.f;
    for (int j = s; j < t; ++j) {
        int r = csr_row[j];
        float w = csr_w[j];
        uint32_t v = *(const uint32_t*)(h_bf + (size_t)r * HDIM + lane * 2);
        a0 += w * bf2f(v & 0xffffu);
        a1 += w * bf2f(v >> 16);
    }
    *(uint32_t*)(agg + (size_t)n * HDIM + lane * 2) = f2bf(a0) | (f2bf(a1) << 16);

    int s2 = row_ptr2[n], t2 = row_ptr2[n + 1];
    float b0 = 0.f, b1 = 0.f;
    for (int j = s2; j < t2; ++j) {
        int e = tcsr[j];
        float2 v = *(const float2*)(out_e + (size_t)e * HDIM + lane * 2);
        b0 += v.x; b1 += v.y;
    }
    float di = deg_inv[n];
    *(uint32_t*)(m_edge_bf + (size_t)n * HDIM + lane * 2) =
        f2bf(b0 * di) | (f2bf(b1 * di) << 16);
}

// ---------------- fused node kernel (bf16 m_edge; GRU ping-pong B) ----------
__global__ __launch_bounds__(512)
void k_node_mega(const uint16_t* __restrict__ m_edge_bf,
                 const uint16_t* __restrict__ agg,
                 float* __restrict__ out_h, uint16_t* __restrict__ h_bf,
                 const float* __restrict__ cpl_cnt, const float* __restrict__ sumw,
                 const short* __restrict__ BTnn, const float* __restrict__ b_nn,
                 const short* __restrict__ BTg1, const float* __restrict__ b_g1,
                 const float* __restrict__ Wg2, const float* __restrict__ b_g2,
                 const short* __restrict__ BTcomb,
                 const short* __restrict__ BTihn, const short* __restrict__ BThhn,
                 const float* __restrict__ b_ih, const float* __restrict__ b_hh)
{
    const int m0 = blockIdx.x * 128;
    __shared__ __align__(16) char Tme[32 * 1024];   // m_edge tile; B buf in GRU
    __shared__ __align__(16) char Tmn[32 * 1024];   // agg -> m_node -> M
    __shared__ __align__(16) char Th [32 * 1024];
    __shared__ __align__(16) char Bt [32 * 1024];
    __shared__ float g_red[4][128];
    __shared__ float g_fin[128];
    __shared__ float sw_s[128];

    const int tid = threadIdx.x, lane = tid & 63;
    const int wid = tid >> 6, wr = wid >> 2, wc = wid & 3;

    stage_bf128(m_edge_bf, nullptr, m0, N_NODES, Tme, tid);
    stage_bf128(agg,       nullptr, m0, N_NODES, Tmn, tid);
    stage_bf128(h_bf,      nullptr, m0, N_NODES, Th,  tid);
    stage_b128(BTnn, 128, 0, 0, Bt, tid);
    if (tid < 128) {
        int n = m0 + tid; if (n >= N_NODES) n = N_NODES - 1;
        sw_s[tid] = sumw[n];
    }
    __syncthreads();

    // ---- phase 0: m_node = agg @ W_nn + sumw*b_nn  -> bf16 into Tmn ----
    {
        f32x4 accM[4][2] = {};
        mfma128(Tmn, Bt, wr, wc, lane, accM);
        __syncthreads();
        #pragma unroll
        for (int ni = 0; ni < 2; ++ni) {
            int col = wc * 32 + ni * 16 + (lane & 15);
            float bv = b_nn[col];
            #pragma unroll
            for (int mi = 0; mi < 4; ++mi)
                #pragma unroll
                for (int j = 0; j < 4; ++j) {
                    int rl = wr * 64 + mi * 16 + ((lane >> 4) << 2) + j;
                    float v = accM[mi][ni][j] + sw_s[rl] * bv;
                    *(uint16_t*)(Tmn + rl * 256 + ((col * 2) ^ ((rl & 7) << 4))) =
                        (uint16_t)f2bf(v);
                }
        }
        __syncthreads();
    }

    // ---- gate GEMM: [me|mn|h](K=384) @ W_g1 ----
    f32x4 accG[4][2] = {};
    #pragma unroll 1
    for (int c = 0; c < 3; ++c) {
        const char* Ac = (c == 0) ? Tme : (c == 1) ? Tmn : Th;
        stage_b128(BTg1, 384, 0, c * 128, Bt, tid);
        __syncthreads();
        mfma128(Ac, Bt, wr, wc, lane, accG);
        __syncthreads();
    }
    {
        float bg[2], wg[2];
        #pragma unroll
        for (int ni = 0; ni < 2; ++ni) {
            int col = wc * 32 + ni * 16 + (lane & 15);
            bg[ni] = b_g1[col]; wg[ni] = Wg2[col];
        }
        #pragma unroll
        for (int mi = 0; mi < 4; ++mi)
            #pragma unroll
            for (int j = 0; j < 4; ++j) {
                float p = fmaxf(accG[mi][0][j] + bg[0], 0.f) * wg[0]
                        + fmaxf(accG[mi][1][j] + bg[1], 0.f) * wg[1];
                #pragma unroll
                for (int o = 8; o; o >>= 1) p += __shfl_xor(p, o);
                if ((lane & 15) == 0)
                    g_red[wc][wr * 64 + mi * 16 + ((lane >> 4) << 2) + j] = p;
            }
    }
    __syncthreads();
    if (tid < 128) {
        float t = g_red[0][tid] + g_red[1][tid] + g_red[2][tid] + g_red[3][tid]
                + b_g2[0];
        g_fin[tid] = 1.f / (1.f + __expf(-t));
    }
    __syncthreads();

    // M = me + g*mn (in place of Tmn); C0 staged alongside
    stage_b128(BTcomb, 256, 0, 0, Bt, tid);
    {
        const int c = tid & 15;
        #pragma unroll
        for (int p = 0; p < 4; ++p) {
            int row = p * 32 + (tid >> 4);
            float g = g_fin[row];
            int sw = (row & 7) << 4;
            #pragma unroll
            for (int hh = 0; hh < 2; ++hh) {
                int off = (c * 8 + hh * 128) ^ sw;
                uint2 me2 = *(uint2*)(Tme + row * 256 + off);
                uint2 mn2 = *(uint2*)(Tmn + row * 256 + off);
                *(uint2*)(Tmn + row * 256 + off) =
                    make_uint2(comb2(me2.x, mn2.x, g), comb2(me2.y, mn2.y, g));
            }
        }
    }
    __syncthreads();    // covers M-combine + C0 stage; Tme now DEAD -> B buffer

    // ---- GRU phases: ping-pong B between Bt and Tme ----
    f32x4 aR[4][2] = {}, aZ[4][2] = {}, aGI[4][2] = {}, aGH[4][2] = {};
    stage_b128(BTcomb, 256, 0, 128, Tme, tid);
    mfma128(Tmn, Bt, wr, wc, lane, aR);   __syncthreads();
    stage_b128(BTcomb, 256, 128, 0, Bt, tid);
    mfma128(Th, Tme, wr, wc, lane, aR);   __syncthreads();
    stage_b128(BTcomb, 256, 128, 128, Tme, tid);
    mfma128(Tmn, Bt, wr, wc, lane, aZ);   __syncthreads();
    stage_b128(BTihn, 128, 0, 0, Bt, tid);
    mfma128(Th, Tme, wr, wc, lane, aZ);   __syncthreads();
    stage_b128(BThhn, 128, 0, 0, Tme, tid);
    mfma128(Tmn, Bt, wr, wc, lane, aGI);  __syncthreads();
    mfma128(Th, Tme, wr, wc, lane, aGH);

    // ---- GRU epilogue (masked); maintains h_bf shadow ----
    #pragma unroll
    for (int ni = 0; ni < 2; ++ni) {
        int col = wc * 32 + ni * 16 + (lane & 15);
        float br  = b_ih[col] + b_hh[col];
        float bz  = b_ih[128 + col] + b_hh[128 + col];
        float bin = b_ih[256 + col], bhn = b_hh[256 + col];
        #pragma unroll
        for (int mi = 0; mi < 4; ++mi)
            #pragma unroll
            for (int j = 0; j < 4; ++j) {
                int node = m0 + wr * 64 + mi * 16 + ((lane >> 4) << 2) + j;
                if (node < N_NODES && cpl_cnt[node] > 0.f) {
                    float r = 1.f / (1.f + __expf(-(aR[mi][ni][j] + br)));
                    float z = 1.f / (1.f + __expf(-(aZ[mi][ni][j] + bz)));
                    float nn = tanhf(aGI[mi][ni][j] + bin + r * (aGH[mi][ni][j] + bhn));
                    size_t hb = (size_t)node * HDIM + col;
                    float hv = out_h[hb];
                    float hn = (1.f - z) * nn + z * hv;
                    out_h[hb] = hn;
                    h_bf[hb] = (uint16_t)f2bf(hn);
                }
            }
    }
}

// ---------------- k_init: small prep (no e-copy) ----------------
// [0,256): h->out_h+h_bf  [256,320): node zero  [320,448): weights  448: detect
#define INIT_BLOCKS 449

__global__ __launch_bounds__(256)
void k_init(const float* __restrict__ h, float* __restrict__ out_h,
            uint16_t* __restrict__ h_bf,
            float* __restrict__ cpl_cnt, float* __restrict__ w_den,
            int* __restrict__ hist, int* __restrict__ counters,
            const uint8_t* __restrict__ tie_raw,
            const float* __restrict__ W_er1, const float* __restrict__ W_er2,
            const float* __restrict__ W_nn, const float* __restrict__ W_g1,
            const float* __restrict__ W_ih, const float* __restrict__ W_hh,
            short* __restrict__ BTer1, short* __restrict__ BTer2,
            short* __restrict__ BTnn, short* __restrict__ BTg1,
            short* __restrict__ BTcomb, short* __restrict__ BTihn,
            short* __restrict__ BThhn)
{
    const int b = blockIdx.x, t = threadIdx.x;
    if (b < 256) {
        for (int i = b * 256 + t; i < N_NODES * HDIM / 4; i += 256 * 256) {
            float4 v = ((const float4*)h)[i];
            ((float4*)out_h)[i] = v;
            *(uint2*)(h_bf + (size_t)i * 4) =
                make_uint2(f2bf(v.x) | (f2bf(v.y) << 16),
                           f2bf(v.z) | (f2bf(v.w) << 16));
        }
    } else if (b < 320) {
        for (int i = (b - 256) * 256 + t; i < N_NODES; i += 64 * 256) {
            cpl_cnt[i] = 0.f; w_den[i] = 0.f; hist[i] = 0;
        }
    } else if (b < 448) {
        for (int i = (b - 320) * 256 + t; i < 384 * 256; i += 128 * 256) {
            {   int n = i / 384, k = i % 384;
                BTer1[i] = (short)f2bf(W_er1[(size_t)k * 256 + n]); }
            if (i < 128 * 256) {
                int n = i / 256, k = i % 256;
                BTer2[i] = (short)f2bf(W_er2[(size_t)k * 128 + n]); }
            if (i < 128 * 128) {
                int n = i / 128, k = i % 128;
                BTnn[i] = (short)f2bf(W_nn[(size_t)k * 128 + n]); }
            if (i < 128 * 384) {
                int n = i / 384, k = i % 384;
                BTg1[i] = (short)f2bf(W_g1[(size_t)k * 128 + n]); }
            if (i < 256 * 256) {
                int n = i >> 8, k = i & 255;
                float v = (k < 128) ? W_ih[n * 128 + k] : W_hh[n * 128 + (k - 128)];
                BTcomb[i] = (short)f2bf(v); }
            if (i < 128 * 128) {
                BTihn[i] = (short)f2bf(W_ih[256 * 128 + i]);
                BThhn[i] = (short)f2bf(W_hh[256 * 128 + i]); }
        }
    } else {
        if (t < 64) {
            int c = 0;
            for (int k = t; k < 4096; k += 64)
                if ((k & 3) && tie_raw[k]) c = 1;
            unsigned long long m = __ballot(c != 0);
            if (t == 0) {
                counters[0] = (m != 0ull) ? 1 : 0;
                counters[1] = 0; counters[2] = 0; counters[3] = 0;
            }
        }
    }
}

// -------- tie classification (wave-aggregated) + copy seg 0 ----------------
__global__ __launch_bounds__(256)
void k_tie(const void* __restrict__ tie_raw, const int* __restrict__ counters,
           const int* __restrict__ ei, float* __restrict__ cpl_cnt,
           int* __restrict__ tie_cnt, int* __restrict__ tie_list,
           int* __restrict__ tie_row, int* __restrict__ tie_col,
           const float* __restrict__ e, float* __restrict__ out_e)
{
    int fmt = counters[0];
    if ((int)blockIdx.x >= EB_CONST) {
        copy_seg(e, out_e, tie_raw, fmt, (int)blockIdx.x - EB_CONST, threadIdx.x, 0);
        return;
    }
    int e_idx = blockIdx.x * 256 + threadIdx.x;
    bool t = false; int r = 0, c = 0;
    if (e_idx < N_EDGES)
        t = fmt ? (((const uint8_t*)tie_raw)[e_idx] != 0)
                : (((const int*)tie_raw)[e_idx] != 0);
    if (t) {
        r = ei[e_idx]; c = ei[N_EDGES + e_idx];
        atomicAdd(&cpl_cnt[r], 1.f);
        atomicAdd(&cpl_cnt[c], 1.f);
    }
    unsigned long long m = __ballot(t);
    if (m == 0ull) return;
    int lane = threadIdx.x & 63;
    int first = __ffsll((unsigned long long)m) - 1;
    int base = 0;
    if (lane == first) base = atomicAdd(tie_cnt, __popcll(m));
    base = __shfl(base, first);
    if (t) {
        int idx = base + __popcll(m & ((1ull << lane) - 1ull));
        if (idx < TIE_CAP) { tie_list[idx] = e_idx; tie_row[idx] = r; tie_col[idx] = c; }
    }
}

// -------- edge weights + copy seg 1 ----------------
__global__ __launch_bounds__(256)
void k_w(const void* __restrict__ tie_raw, const int* __restrict__ counters,
         const int* __restrict__ ei, const float* __restrict__ attr,
         const float* __restrict__ cpl_cnt, float* __restrict__ w_den,
         float* __restrict__ w_arr, int* __restrict__ hist,
         const float* __restrict__ e, float* __restrict__ out_e)
{
    int fmt = counters[0];
    if ((int)blockIdx.x >= EB_CONST) {
        copy_seg(e, out_e, tie_raw, fmt, (int)blockIdx.x - EB_CONST, threadIdx.x, 1);
        return;
    }
    int e_idx = blockIdx.x * 256 + threadIdx.x;
    if (e_idx >= N_EDGES) return;
    bool t = fmt ? (((const uint8_t*)tie_raw)[e_idx] != 0)
                 : (((const int*)tie_raw)[e_idx] != 0);
    float w = 0.f;
    if (!t) {
        int c = ei[N_EDGES + e_idx];
        if (cpl_cnt[c] > 0.f) {
            float X = fabsf(attr[(size_t)e_idx * 10 + 1]);
            w = 1.f / sqrtf(X * X + 1e-6f);
            atomicAdd(&w_den[c], w);
            atomicAdd(&hist[c], 1);
        }
    }
    w_arr[e_idx] = w;
}

// ---------------- dual CSR build ----------------
__global__ __launch_bounds__(SCAN_B)
void k_scan1(const int* __restrict__ hist, const float* __restrict__ cpl_cnt,
             int* __restrict__ excl, int* __restrict__ bsum,
             int* __restrict__ excl2, int* __restrict__ bsum2)
{
    __shared__ int s[SCAN_B];
    int t = threadIdx.x;
    int i = blockIdx.x * SCAN_B + t;
    int v = (i < N_NODES) ? hist[i] : 0;
    s[t] = v;
    __syncthreads();
    for (int o = 1; o < SCAN_B; o <<= 1) {
        int u = (t >= o) ? s[t - o] : 0;
        __syncthreads();
        s[t] += u;
        __syncthreads();
    }
    if (i < N_NODES) excl[i] = s[t] - v;
    if (t == SCAN_B - 1) bsum[blockIdx.x] = s[t];
    __syncthreads();
    int v2 = (i < N_NODES) ? (int)cpl_cnt[i] : 0;
    s[t] = v2;
    __syncthreads();
    for (int o = 1; o < SCAN_B; o <<= 1) {
        int u = (t >= o) ? s[t - o] : 0;
        __syncthreads();
        s[t] += u;
        __syncthreads();
    }
    if (i < N_NODES) excl2[i] = s[t] - v2;
    if (t == SCAN_B - 1) bsum2[blockIdx.x] = s[t];
}

__global__ void k_scan2(int* __restrict__ bsum, int* __restrict__ bsum2,
                        int* __restrict__ counters)
{
    const int NB = (N_NODES + SCAN_B - 1) / SCAN_B;
    if (threadIdx.x == 0) {
        int run = 0;
        for (int b = 0; b < NB; ++b) { int x = bsum[b]; bsum[b] = run; run += x; }
        counters[2] = run;
        int run2 = 0;
        for (int b = 0; b < NB; ++b) { int x = bsum2[b]; bsum2[b] = run2; run2 += x; }
        counters[3] = run2;
    }
}

__global__ __launch_bounds__(256)
void k_scan3(const int* __restrict__ excl, const int* __restrict__ bsum,
             const int* __restrict__ excl2, const int* __restrict__ bsum2,
             int* __restrict__ row_ptr, int* __restrict__ cursor,
             int* __restrict__ row_ptr2, int* __restrict__ cursor2,
             const int* __restrict__ counters,
             const float* __restrict__ cpl_cnt, const float* __restrict__ w_den,
             float* __restrict__ deg_inv, float* __restrict__ sumw)
{
    int i = blockIdx.x * 256 + threadIdx.x;
    if (i < N_NODES) {
        int v = excl[i] + bsum[i >> 8];
        row_ptr[i] = v;  cursor[i] = v;
        int v2 = excl2[i] + bsum2[i >> 8];
        row_ptr2[i] = v2; cursor2[i] = v2;
        deg_inv[i] = 1.f / fmaxf(cpl_cnt[i], 1.f);
        float wd = w_den[i];
        sumw[i] = wd / (wd + 1e-6f);
    }
    if (i == N_NODES) {
        row_ptr[N_NODES] = counters[2];
        row_ptr2[N_NODES] = counters[3];
    }
}

// -------- CSR fills + copy seg 2 ----------------
__global__ __launch_bounds__(256)
void k_fill(const int* __restrict__ ei, const float* __restrict__ w_arr,
            const float* __restrict__ w_den, int* __restrict__ cursor,
            int* __restrict__ csr_row, float* __restrict__ csr_w,
            const int* __restrict__ counters, const int* __restrict__ tie_list,
            const int* __restrict__ tie_row, const int* __restrict__ tie_col,
            int* __restrict__ cursor2, int* __restrict__ tcsr,
            const void* __restrict__ tie_raw,
            const float* __restrict__ e, float* __restrict__ out_e)
{
    int b = blockIdx.x;
    if (b >= EB_CONST + TB_CONST) {
        copy_seg(e, out_e, tie_raw, counters[0], b - (EB_CONST + TB_CONST),
                 threadIdx.x, 2);
        return;
    }
    if (b < EB_CONST) {
        int e_idx = b * 256 + threadIdx.x;
        if (e_idx >= N_EDGES) return;
        float w = w_arr[e_idx];
        if (w == 0.f) return;
        int c = ei[N_EDGES + e_idx];
        int pos = atomicAdd(&cursor[c], 1);
        csr_row[pos] = ei[e_idx];
        csr_w[pos] = w / (w_den[c] + 1e-6f);
    } else {
        int i = (b - EB_CONST) * 256 + threadIdx.x;
        int cnt = counters[1]; if (cnt > TIE_CAP) cnt = TIE_CAP;
        if (i < cnt) {
            int e_idx = tie_list[i];
            int p1 = atomicAdd(&cursor2[tie_row[i]], 1); tcsr[p1] = e_idx;
            int p2 = atomicAdd(&cursor2[tie_col[i]], 1); tcsr[p2] = e_idx;
        }
    }
}

// ---------------- launch ----------------
extern "C" void kernel_launch(void* const* d_in, const int* in_sizes, int n_in,
                              void* d_out, int out_size, void* d_ws, size_t ws_size,
                              hipStream_t stream)
{
    const float* h     = (const float*)d_in[0];
    const float* e     = (const float*)d_in[1];
    const float* attr  = (const float*)d_in[2];
    const float* W_er1 = (const float*)d_in[3];
    const float* b_er1 = (const float*)d_in[4];
    const float* W_er2 = (const float*)d_in[5];
    const float* b_er2 = (const float*)d_in[6];
    const float* W_ih  = (const float*)d_in[7];
    const float* W_hh  = (const float*)d_in[8];
    const float* b_ih  = (const float*)d_in[9];
    const float* b_hh  = (const float*)d_in[10];
    const float* W_nn  = (const float*)d_in[11];
    const float* b_nn  = (const float*)d_in[12];
    const float* W_g1  = (const float*)d_in[13];
    const float* b_g1  = (const float*)d_in[14];
    const float* W_g2  = (const float*)d_in[15];
    const float* b_g2  = (const float*)d_in[16];
    const int*   ei    = (const int*)d_in[17];
    const void*  tie_raw = d_in[18];

    float* out_h = (float*)d_out;
    float* out_e = out_h + (size_t)N_NODES * HDIM;

    char* ws = (char*)d_ws;
    size_t off = 0;
    auto alloc = [&](size_t bytes) -> void* {
        void* p = ws + off;
        off = (off + bytes + 255) & ~(size_t)255;
        return p;
    };
    float* cpl_cnt = (float*)alloc((size_t)N_NODES * 4);
    float* w_den   = (float*)alloc((size_t)N_NODES * 4);
    int*   hist    = (int*)  alloc((size_t)N_NODES * 4);
    int*   counters= (int*)  alloc(256);  // [0]=fmt [1]=tie_cnt [2]=csr [3]=tcsr
    float* deg_inv = (float*)alloc((size_t)N_NODES * 4);
    float* sumw    = (float*)alloc((size_t)N_NODES * 4);
    float* w_arr   = (float*)alloc((size_t)N_EDGES * 4);
    int* tie_list  = (int*)alloc((size_t)TIE_CAP * 4);
    int* tie_row   = (int*)alloc((size_t)TIE_CAP * 4);
    int* tie_col   = (int*)alloc((size_t)TIE_CAP * 4);
    short* BTer1   = (short*)alloc((size_t)256 * 384 * 2);
    short* BTer2   = (short*)alloc((size_t)128 * 256 * 2);
    short* BTnn    = (short*)alloc((size_t)128 * 128 * 2);
    short* BTg1    = (short*)alloc((size_t)128 * 384 * 2);
    short* BTcomb  = (short*)alloc((size_t)256 * 256 * 2);
    short* BTihn   = (short*)alloc((size_t)128 * 128 * 2);
    short* BThhn   = (short*)alloc((size_t)128 * 128 * 2);
    uint16_t* h_bf = (uint16_t*)alloc((size_t)N_NODES * HDIM * 2);
    uint16_t* agg  = (uint16_t*)alloc((size_t)N_NODES * HDIM * 2);
    uint16_t* m_edge_bf = (uint16_t*)alloc((size_t)N_NODES * HDIM * 2);
    int* excl      = (int*)alloc((size_t)N_NODES * 4);
    int* excl2     = (int*)alloc((size_t)N_NODES * 4);
    int* bsum      = (int*)alloc(256 * 4);
    int* bsum2     = (int*)alloc(256 * 4);
    int* row_ptr   = (int*)alloc((size_t)(N_NODES + 1) * 4);
    int* row_ptr2  = (int*)alloc((size_t)(N_NODES + 1) * 4);
    int* cursor    = (int*)alloc((size_t)N_NODES * 4);
    int* cursor2   = (int*)alloc((size_t)N_NODES * 4);
    int* csr_row   = (int*)alloc((size_t)N_EDGES * 4);
    float* csr_w   = (float*)alloc((size_t)N_EDGES * 4);
    int* tcsr      = (int*)alloc((size_t)2 * TIE_CAP * 4);
    if (off > ws_size) return;

    const int GM_N = (N_NODES + 127) / 128;          // 391
    const int NB   = (N_NODES + SCAN_B - 1) / SCAN_B;

    k_init<<<INIT_BLOCKS, 256, 0, stream>>>(
        h, out_h, h_bf, cpl_cnt, w_den, hist, counters,
        (const uint8_t*)tie_raw,
        W_er1, W_er2, W_nn, W_g1, W_ih, W_hh,
        BTer1, BTer2, BTnn, BTg1, BTcomb, BTihn, BThhn);
    k_tie<<<EB_CONST + CPB, 256, 0, stream>>>(
        tie_raw, counters, ei, cpl_cnt, counters + 1,
        tie_list, tie_row, tie_col, e, out_e);
    k_w<<<EB_CONST + CPB, 256, 0, stream>>>(
        tie_raw, counters, ei, attr, cpl_cnt, w_den, w_arr, hist, e, out_e);
    k_scan1<<<NB, SCAN_B, 0, stream>>>(hist, cpl_cnt, excl, bsum, excl2, bsum2);
    k_scan2<<<1, 64, 0, stream>>>(bsum, bsum2, counters);
    k_scan3<<<(N_NODES + 256) / 256, 256, 0, stream>>>(
        excl, bsum, excl2, bsum2, row_ptr, cursor, row_ptr2, cursor2,
        counters, cpl_cnt, w_den, deg_inv, sumw);
    k_fill<<<EB_CONST + TB_CONST + CPB, 256, 0, stream>>>(
        ei, w_arr, w_den, cursor, csr_row, csr_w,
        counters, tie_list, tie_row, tie_col, cursor2, tcsr,
        tie_raw, e, out_e);

    for (int it = 0; it < NITER; ++it) {
        const float* e_src = (it == 0) ? e : out_e;
        k_tie_fused<<<GM_T, 512, 0, stream>>>(
            e_src, out_e, counters, h_bf, tie_list, tie_row, tie_col,
            BTer1, BTer2, b_er1, b_er2);
        k_gather<<<(N_NODES + 3) / 4, 256, 0, stream>>>(
            row_ptr, csr_row, csr_w, h_bf, agg,
            row_ptr2, tcsr, out_e, deg_inv, m_edge_bf);
        k_node_mega<<<GM_N, 512, 0, stream>>>(
            m_edge_bf, agg, out_h, h_bf, cpl_cnt, sumw,
            BTnn, b_nn, BTg1, b_g1, W_g2, b_g2,
            BTcomb, BTihn, BThhn, b_ih, b_hh);
    }
}

// Round 14
// 853.357 us; speedup vs baseline: 1.1481x; 1.1426x over previous
//
#include <hip/hip_runtime.h>
#include <cstdint>

#define N_NODES 50000
#define N_EDGES 800000
#define HDIM    128
#define TIE_CAP 44000
#define NITER   2
#define SCAN_B  256
#define EB_CONST 3125            // N_EDGES/256
#define TB_CONST 172             // ceil(TIE_CAP/256)

typedef __attribute__((ext_vector_type(8))) short bf16x8;
typedef __attribute__((ext_vector_type(4))) float f32x4;

__device__ __forceinline__ uint32_t f2bf(float f) {
    uint32_t u = __builtin_bit_cast(uint32_t, f);
    return (u + 0x7fffu + ((u >> 16) & 1u)) >> 16;   // RNE
}
__device__ __forceinline__ float bf2f(uint32_t b) {
    return __builtin_bit_cast(float, b << 16);
}
__device__ __forceinline__ uint32_t comb2(uint32_t me, uint32_t mn, float g) {
    float a0 = bf2f(me & 0xffffu) + g * bf2f(mn & 0xffffu);
    float a1 = bf2f(me >> 16)     + g * bf2f(mn >> 16);
    return f2bf(a0) | (f2bf(a1) << 16);
}

// ---- LDS tiles: [128 rows][128 bf16] = 256B rows, byte ^= (row&7)<<4 ----

__device__ __forceinline__ void stage_a128(const float* __restrict__ base,
                                           const int* __restrict__ gidx,
                                           int m0, int Mlim, char* tile, int tid)
{
    const int c = tid & 15;
    #pragma unroll
    for (int p = 0; p < 4; ++p) {
        int row = p * 32 + (tid >> 4);
        int ar = m0 + row; if (ar >= Mlim) ar = Mlim - 1;
        long g = gidx ? gidx[ar] : ar;
        const float* s = base + g * HDIM + c * 4;
        float4 v0 = *(const float4*)s;
        float4 v1 = *(const float4*)(s + 64);
        uint2 w0 = make_uint2(f2bf(v0.x) | (f2bf(v0.y) << 16),
                              f2bf(v0.z) | (f2bf(v0.w) << 16));
        uint2 w1 = make_uint2(f2bf(v1.x) | (f2bf(v1.y) << 16),
                              f2bf(v1.z) | (f2bf(v1.w) << 16));
        int sw = (row & 7) << 4;
        *(uint2*)(tile + row * 256 + ((c * 8) ^ sw)) = w0;
        *(uint2*)(tile + row * 256 + ((c * 8 + 128) ^ sw)) = w1;
    }
}

__device__ __forceinline__ void stage_bf128(const uint16_t* __restrict__ base,
                                            const int* __restrict__ gidx,
                                            int m0, int Mlim, char* tile, int tid)
{
    const int c = tid & 15;
    #pragma unroll
    for (int p = 0; p < 4; ++p) {
        int row = p * 32 + (tid >> 4);
        int ar = m0 + row; if (ar >= Mlim) ar = Mlim - 1;
        long g = gidx ? gidx[ar] : ar;
        uint4 v = *(const uint4*)(base + g * HDIM + c * 8);
        *(uint4*)(tile + row * 256 + ((c * 16) ^ ((row & 7) << 4))) = v;
    }
}

__device__ __forceinline__ void stage_b128(const short* __restrict__ BT, int ldk,
                                           int n0, int k0, char* tile, int tid)
{
    const int c = tid & 15;
    #pragma unroll
    for (int p = 0; p < 4; ++p) {
        int n = p * 32 + (tid >> 4);
        uint4 v = *(const uint4*)&BT[(size_t)(n0 + n) * ldk + k0 + c * 8];
        *(uint4*)(tile + n * 256 + ((c * 16) ^ ((n & 7) << 4))) = v;
    }
}

// one K=128 chunk: 8 waves in 2(M)x4(N); wave does 64x32 via 16x16x32 MFMA
__device__ __forceinline__ void mfma128(const char* At, const char* Bt,
                                        int wr, int wc, int lane, f32x4 acc[4][2])
{
    #pragma unroll
    for (int ks = 0; ks < 4; ++ks) {
        int kb = ks * 64 + (lane >> 4) * 16;
        bf16x8 aF[4], bF[2];
        #pragma unroll
        for (int mi = 0; mi < 4; ++mi) {
            int row = wr * 64 + mi * 16 + (lane & 15);
            aF[mi] = *(const bf16x8*)(At + row * 256 + (kb ^ ((row & 7) << 4)));
        }
        #pragma unroll
        for (int ni = 0; ni < 2; ++ni) {
            int n = wc * 32 + ni * 16 + (lane & 15);
            bF[ni] = *(const bf16x8*)(Bt + n * 256 + (kb ^ ((n & 7) << 4)));
        }
        #pragma unroll
        for (int mi = 0; mi < 4; ++mi)
            #pragma unroll
            for (int ni = 0; ni < 2; ++ni)
                acc[mi][ni] = __builtin_amdgcn_mfma_f32_16x16x32_bf16(
                    aF[mi], bF[ni], acc[mi][ni], 0, 0, 0);
    }
}

// ---------------- fused tie-edge kernel (pipelined A double-buffer) ---------
__global__ __launch_bounds__(512)
void k_tie_fused(const float* __restrict__ e_src, float* __restrict__ out_e,
                 const int* __restrict__ counters,
                 const uint16_t* __restrict__ h_bf,
                 const int* __restrict__ tie_list, const int* __restrict__ tie_row,
                 const int* __restrict__ tie_col,
                 const short* __restrict__ BTer1, const short* __restrict__ BTer2,
                 const float* __restrict__ b_er1, const float* __restrict__ b_er2)
{
    int cnt = counters[1]; if (cnt > TIE_CAP) cnt = TIE_CAP;
    const int m0 = blockIdx.x * 128;
    if (m0 >= cnt) return;

    __shared__ __align__(16) char At0[32 * 1024];
    __shared__ __align__(16) char At1[32 * 1024];
    __shared__ __align__(16) char B0[32 * 1024];
    __shared__ __align__(16) char B1[32 * 1024];

    const int tid = threadIdx.x, lane = tid & 63;
    const int wid = tid >> 6, wr = wid >> 2, wc = wid & 3;

    f32x4 acc0[4][2] = {}, acc1[4][2] = {};

    // prologue: A(0)=e rows, B(c=0)
    stage_a128(e_src, tie_list, m0, cnt, At0, tid);
    stage_b128(BTer1, 384, 0,   0, B0, tid);
    stage_b128(BTer1, 384, 128, 0, B1, tid);
    __syncthreads();

    // c = 0: compute on At0, prefetch A(1)=h[row] into At1
    stage_bf128(h_bf, tie_row, m0, cnt, At1, tid);
    mfma128(At0, B0, wr, wc, lane, acc0);
    mfma128(At0, B1, wr, wc, lane, acc1);
    __syncthreads();
    stage_b128(BTer1, 384, 0,   128, B0, tid);
    stage_b128(BTer1, 384, 128, 128, B1, tid);
    __syncthreads();

    // c = 1: compute on At1, prefetch A(2)=h[col] into At0 (c0 reads done)
    stage_bf128(h_bf, tie_col, m0, cnt, At0, tid);
    mfma128(At1, B0, wr, wc, lane, acc0);
    mfma128(At1, B1, wr, wc, lane, acc1);
    __syncthreads();
    stage_b128(BTer1, 384, 0,   256, B0, tid);
    stage_b128(BTer1, 384, 128, 256, B1, tid);
    __syncthreads();

    // c = 2
    mfma128(At0, B0, wr, wc, lane, acc0);
    mfma128(At0, B1, wr, wc, lane, acc1);
    __syncthreads();   // all reads of At0/At1/B0/B1 done

    // epilogue1: relu(acc+b) -> bf16 C1 (C1a k0-127 -> At1, C1b k128-255 -> At0)
    // and stage BOTH BTer2 K-halves into B0/B1 in the same phase.
    stage_b128(BTer2, 256, 0, 0,   B0, tid);
    stage_b128(BTer2, 256, 0, 128, B1, tid);
    #pragma unroll
    for (int half = 0; half < 2; ++half) {
        char* Ct = half ? At0 : At1;
        #pragma unroll
        for (int ni = 0; ni < 2; ++ni) {
            int col = wc * 32 + ni * 16 + (lane & 15);
            float bv = b_er1[half * 128 + col];
            #pragma unroll
            for (int mi = 0; mi < 4; ++mi)
                #pragma unroll
                for (int j = 0; j < 4; ++j) {
                    int rl = wr * 64 + mi * 16 + ((lane >> 4) << 2) + j;
                    float v = fmaxf((half ? acc1 : acc0)[mi][ni][j] + bv, 0.f);
                    *(uint16_t*)(Ct + rl * 256 + ((col * 2) ^ ((rl & 7) << 4))) =
                        (uint16_t)f2bf(v);
                }
        }
    }
    __syncthreads();

    // L2: acc2 = C1a @ B2a + C1b @ B2b
    f32x4 acc2[4][2] = {};
    mfma128(At1, B0, wr, wc, lane, acc2);
    mfma128(At0, B1, wr, wc, lane, acc2);

    // epilogue2: out_e[tie] = e_src[tie] + eref
    int col0 = wc * 32 + (lane & 15);
    float bv0 = b_er2[col0], bv1 = b_er2[col0 + 16];
    #pragma unroll
    for (int mi = 0; mi < 4; ++mi) {
        #pragma unroll
        for (int j = 0; j < 4; ++j) {
            int i = m0 + wr * 64 + mi * 16 + ((lane >> 4) << 2) + j;
            if (i < cnt) {
                int e = tie_list[i];
                #pragma unroll
                for (int ni = 0; ni < 2; ++ni) {
                    int col = col0 + ni * 16;
                    size_t eb = (size_t)e * HDIM + col;
                    out_e[eb] = e_src[eb] + acc2[mi][ni][j] + (ni ? bv1 : bv0);
                }
            }
        }
    }
}

// ---------------- gather: agg + m_edge (tie-CSR), per node ------------------
__global__ __launch_bounds__(256)
void k_gather(const int* __restrict__ row_ptr, const int* __restrict__ csr_row,
              const float* __restrict__ csr_w, const uint16_t* __restrict__ h_bf,
              uint16_t* __restrict__ agg,
              const int* __restrict__ row_ptr2, const int* __restrict__ tcsr,
              const float* __restrict__ out_e, const float* __restrict__ deg_inv,
              uint16_t* __restrict__ m_edge_bf)
{
    int n = blockIdx.x * 4 + (threadIdx.x >> 6);
    if (n >= N_NODES) return;
    int lane = threadIdx.x & 63;

    int s = row_ptr[n], t = row_ptr[n + 1];
    float a0 = 0.f, a1 = 0.f;
    for (int j = s; j < t; ++j) {
        int r = csr_row[j];
        float w = csr_w[j];
        uint32_t v = *(const uint32_t*)(h_bf + (size_t)r * HDIM + lane * 2);
        a0 += w * bf2f(v & 0xffffu);
        a1 += w * bf2f(v >> 16);
    }
    *(uint32_t*)(agg + (size_t)n * HDIM + lane * 2) = f2bf(a0) | (f2bf(a1) << 16);

    int s2 = row_ptr2[n], t2 = row_ptr2[n + 1];
    float b0 = 0.f, b1 = 0.f;
    for (int j = s2; j < t2; ++j) {
        int e = tcsr[j];
        float2 v = *(const float2*)(out_e + (size_t)e * HDIM + lane * 2);
        b0 += v.x; b1 += v.y;
    }
    float di = deg_inv[n];
    *(uint32_t*)(m_edge_bf + (size_t)n * HDIM + lane * 2) =
        f2bf(b0 * di) | (f2bf(b1 * di) << 16);
}

// ---------------- fused node kernel (bf16 m_edge; GRU ping-pong B) ----------
__global__ __launch_bounds__(512)
void k_node_mega(const uint16_t* __restrict__ m_edge_bf,
                 const uint16_t* __restrict__ agg,
                 float* __restrict__ out_h, uint16_t* __restrict__ h_bf,
                 const float* __restrict__ cpl_cnt, const float* __restrict__ sumw,
                 const short* __restrict__ BTnn, const float* __restrict__ b_nn,
                 const short* __restrict__ BTg1, const float* __restrict__ b_g1,
                 const float* __restrict__ Wg2, const float* __restrict__ b_g2,
                 const short* __restrict__ BTcomb,
                 const short* __restrict__ BTihn, const short* __restrict__ BThhn,
                 const float* __restrict__ b_ih, const float* __restrict__ b_hh)
{
    const int m0 = blockIdx.x * 128;
    __shared__ __align__(16) char Tme[32 * 1024];   // m_edge tile; B buf in GRU
    __shared__ __align__(16) char Tmn[32 * 1024];   // agg -> m_node -> M
    __shared__ __align__(16) char Th [32 * 1024];
    __shared__ __align__(16) char Bt [32 * 1024];
    __shared__ float g_red[4][128];
    __shared__ float g_fin[128];
    __shared__ float sw_s[128];

    const int tid = threadIdx.x, lane = tid & 63;
    const int wid = tid >> 6, wr = wid >> 2, wc = wid & 3;

    stage_bf128(m_edge_bf, nullptr, m0, N_NODES, Tme, tid);
    stage_bf128(agg,       nullptr, m0, N_NODES, Tmn, tid);
    stage_bf128(h_bf,      nullptr, m0, N_NODES, Th,  tid);
    stage_b128(BTnn, 128, 0, 0, Bt, tid);
    if (tid < 128) {
        int n = m0 + tid; if (n >= N_NODES) n = N_NODES - 1;
        sw_s[tid] = sumw[n];
    }
    __syncthreads();

    // ---- phase 0: m_node = agg @ W_nn + sumw*b_nn  -> bf16 into Tmn ----
    {
        f32x4 accM[4][2] = {};
        mfma128(Tmn, Bt, wr, wc, lane, accM);
        __syncthreads();
        #pragma unroll
        for (int ni = 0; ni < 2; ++ni) {
            int col = wc * 32 + ni * 16 + (lane & 15);
            float bv = b_nn[col];
            #pragma unroll
            for (int mi = 0; mi < 4; ++mi)
                #pragma unroll
                for (int j = 0; j < 4; ++j) {
                    int rl = wr * 64 + mi * 16 + ((lane >> 4) << 2) + j;
                    float v = accM[mi][ni][j] + sw_s[rl] * bv;
                    *(uint16_t*)(Tmn + rl * 256 + ((col * 2) ^ ((rl & 7) << 4))) =
                        (uint16_t)f2bf(v);
                }
        }
        __syncthreads();
    }

    // ---- gate GEMM: [me|mn|h](K=384) @ W_g1 ----
    f32x4 accG[4][2] = {};
    #pragma unroll 1
    for (int c = 0; c < 3; ++c) {
        const char* Ac = (c == 0) ? Tme : (c == 1) ? Tmn : Th;
        stage_b128(BTg1, 384, 0, c * 128, Bt, tid);
        __syncthreads();
        mfma128(Ac, Bt, wr, wc, lane, accG);
        __syncthreads();
    }
    {
        float bg[2], wg[2];
        #pragma unroll
        for (int ni = 0; ni < 2; ++ni) {
            int col = wc * 32 + ni * 16 + (lane & 15);
            bg[ni] = b_g1[col]; wg[ni] = Wg2[col];
        }
        #pragma unroll
        for (int mi = 0; mi < 4; ++mi)
            #pragma unroll
            for (int j = 0; j < 4; ++j) {
                float p = fmaxf(accG[mi][0][j] + bg[0], 0.f) * wg[0]
                        + fmaxf(accG[mi][1][j] + bg[1], 0.f) * wg[1];
                #pragma unroll
                for (int o = 8; o; o >>= 1) p += __shfl_xor(p, o);
                if ((lane & 15) == 0)
                    g_red[wc][wr * 64 + mi * 16 + ((lane >> 4) << 2) + j] = p;
            }
    }
    __syncthreads();
    if (tid < 128) {
        float t = g_red[0][tid] + g_red[1][tid] + g_red[2][tid] + g_red[3][tid]
                + b_g2[0];
        g_fin[tid] = 1.f / (1.f + __expf(-t));
    }
    __syncthreads();

    // M = me + g*mn (in place of Tmn); C0 staged alongside
    stage_b128(BTcomb, 256, 0, 0, Bt, tid);
    {
        const int c = tid & 15;
        #pragma unroll
        for (int p = 0; p < 4; ++p) {
            int row = p * 32 + (tid >> 4);
            float g = g_fin[row];
            int sw = (row & 7) << 4;
            #pragma unroll
            for (int hh = 0; hh < 2; ++hh) {
                int off = (c * 8 + hh * 128) ^ sw;
                uint2 me2 = *(uint2*)(Tme + row * 256 + off);
                uint2 mn2 = *(uint2*)(Tmn + row * 256 + off);
                *(uint2*)(Tmn + row * 256 + off) =
                    make_uint2(comb2(me2.x, mn2.x, g), comb2(me2.y, mn2.y, g));
            }
        }
    }
    __syncthreads();    // covers M-combine + C0 stage; Tme now DEAD -> B buffer

    // ---- GRU phases: ping-pong B between Bt and Tme ----
    f32x4 aR[4][2] = {}, aZ[4][2] = {}, aGI[4][2] = {}, aGH[4][2] = {};
    stage_b128(BTcomb, 256, 0, 128, Tme, tid);
    mfma128(Tmn, Bt, wr, wc, lane, aR);   __syncthreads();
    stage_b128(BTcomb, 256, 128, 0, Bt, tid);
    mfma128(Th, Tme, wr, wc, lane, aR);   __syncthreads();
    stage_b128(BTcomb, 256, 128, 128, Tme, tid);
    mfma128(Tmn, Bt, wr, wc, lane, aZ);   __syncthreads();
    stage_b128(BTihn, 128, 0, 0, Bt, tid);
    mfma128(Th, Tme, wr, wc, lane, aZ);   __syncthreads();
    stage_b128(BThhn, 128, 0, 0, Tme, tid);
    mfma128(Tmn, Bt, wr, wc, lane, aGI);  __syncthreads();
    mfma128(Th, Tme, wr, wc, lane, aGH);

    // ---- GRU epilogue (masked); maintains h_bf shadow ----
    #pragma unroll
    for (int ni = 0; ni < 2; ++ni) {
        int col = wc * 32 + ni * 16 + (lane & 15);
        float br  = b_ih[col] + b_hh[col];
        float bz  = b_ih[128 + col] + b_hh[128 + col];
        float bin = b_ih[256 + col], bhn = b_hh[256 + col];
        #pragma unroll
        for (int mi = 0; mi < 4; ++mi)
            #pragma unroll
            for (int j = 0; j < 4; ++j) {
                int node = m0 + wr * 64 + mi * 16 + ((lane >> 4) << 2) + j;
                if (node < N_NODES && cpl_cnt[node] > 0.f) {
                    float r = 1.f / (1.f + __expf(-(aR[mi][ni][j] + br)));
                    float z = 1.f / (1.f + __expf(-(aZ[mi][ni][j] + bz)));
                    float nn = tanhf(aGI[mi][ni][j] + bin + r * (aGH[mi][ni][j] + bhn));
                    size_t hb = (size_t)node * HDIM + col;
                    float hv = out_h[hb];
                    float hn = (1.f - z) * nn + z * hv;
                    out_h[hb] = hn;
                    h_bf[hb] = (uint16_t)f2bf(hn);
                }
            }
    }
}

// ---------------- k_init: block-partitioned prep (incl. e-copy) -------------
// [0,2048): e->out_e  [2048,2304): h->out_h+h_bf  [2304,2368): node zero
// [2368,2496): weights  2496: fmt detect
#define INIT_BLOCKS 2497

__global__ __launch_bounds__(256)
void k_init(const float* __restrict__ e, float* __restrict__ out_e,
            const float* __restrict__ h, float* __restrict__ out_h,
            uint16_t* __restrict__ h_bf,
            float* __restrict__ cpl_cnt, float* __restrict__ w_den,
            int* __restrict__ hist, int* __restrict__ counters,
            const uint8_t* __restrict__ tie_raw,
            const float* __restrict__ W_er1, const float* __restrict__ W_er2,
            const float* __restrict__ W_nn, const float* __restrict__ W_g1,
            const float* __restrict__ W_ih, const float* __restrict__ W_hh,
            short* __restrict__ BTer1, short* __restrict__ BTer2,
            short* __restrict__ BTnn, short* __restrict__ BTg1,
            short* __restrict__ BTcomb, short* __restrict__ BTihn,
            short* __restrict__ BThhn)
{
    const int b = blockIdx.x, t = threadIdx.x;
    if (b < 2048) {
        const float4* src = (const float4*)e;
        float4* dst = (float4*)out_e;
        for (int i = b * 256 + t; i < N_EDGES * HDIM / 4; i += 2048 * 256)
            dst[i] = src[i];
    } else if (b < 2304) {
        for (int i = (b - 2048) * 256 + t; i < N_NODES * HDIM / 4; i += 256 * 256) {
            float4 v = ((const float4*)h)[i];
            ((float4*)out_h)[i] = v;
            *(uint2*)(h_bf + (size_t)i * 4) =
                make_uint2(f2bf(v.x) | (f2bf(v.y) << 16),
                           f2bf(v.z) | (f2bf(v.w) << 16));
        }
    } else if (b < 2368) {
        for (int i = (b - 2304) * 256 + t; i < N_NODES; i += 64 * 256) {
            cpl_cnt[i] = 0.f; w_den[i] = 0.f; hist[i] = 0;
        }
    } else if (b < 2496) {
        for (int i = (b - 2368) * 256 + t; i < 384 * 256; i += 128 * 256) {
            {   int n = i / 384, k = i % 384;
                BTer1[i] = (short)f2bf(W_er1[(size_t)k * 256 + n]); }
            if (i < 128 * 256) {
                int n = i / 256, k = i % 256;
                BTer2[i] = (short)f2bf(W_er2[(size_t)k * 128 + n]); }
            if (i < 128 * 128) {
                int n = i / 128, k = i % 128;
                BTnn[i] = (short)f2bf(W_nn[(size_t)k * 128 + n]); }
            if (i < 128 * 384) {
                int n = i / 384, k = i % 384;
                BTg1[i] = (short)f2bf(W_g1[(size_t)k * 128 + n]); }
            if (i < 256 * 256) {
                int n = i >> 8, k = i & 255;
                float v = (k < 128) ? W_ih[n * 128 + k] : W_hh[n * 128 + (k - 128)];
                BTcomb[i] = (short)f2bf(v); }
            if (i < 128 * 128) {
                BTihn[i] = (short)f2bf(W_ih[256 * 128 + i]);
                BThhn[i] = (short)f2bf(W_hh[256 * 128 + i]); }
        }
    } else {
        if (t < 64) {
            int c = 0;
            for (int k = t; k < 4096; k += 64)
                if ((k & 3) && tie_raw[k]) c = 1;
            unsigned long long m = __ballot(c != 0);
            if (t == 0) {
                counters[0] = (m != 0ull) ? 1 : 0;
                counters[1] = 0; counters[2] = 0; counters[3] = 0;
            }
        }
    }
}

// ---------------- tie classification (wave-aggregated compaction) -----------
__global__ __launch_bounds__(256)
void k_tie(const void* __restrict__ tie_raw, const int* __restrict__ counters,
           const int* __restrict__ ei, float* __restrict__ cpl_cnt,
           int* __restrict__ tie_cnt, int* __restrict__ tie_list,
           int* __restrict__ tie_row, int* __restrict__ tie_col)
{
    int e = blockIdx.x * 256 + threadIdx.x;
    int fmt = counters[0];
    bool t = false; int r = 0, c = 0;
    if (e < N_EDGES)
        t = fmt ? (((const uint8_t*)tie_raw)[e] != 0)
                : (((const int*)tie_raw)[e] != 0);
    if (t) {
        r = ei[e]; c = ei[N_EDGES + e];
        atomicAdd(&cpl_cnt[r], 1.f);
        atomicAdd(&cpl_cnt[c], 1.f);
    }
    unsigned long long m = __ballot(t);
    if (m == 0ull) return;
    int lane = threadIdx.x & 63;
    int first = __ffsll((unsigned long long)m) - 1;
    int base = 0;
    if (lane == first) base = atomicAdd(tie_cnt, __popcll(m));
    base = __shfl(base, first);
    if (t) {
        int idx = base + __popcll(m & ((1ull << lane) - 1ull));
        if (idx < TIE_CAP) { tie_list[idx] = e; tie_row[idx] = r; tie_col[idx] = c; }
    }
}

__global__ __launch_bounds__(256)
void k_w(const void* __restrict__ tie_raw, const int* __restrict__ counters,
         const int* __restrict__ ei, const float* __restrict__ attr,
         const float* __restrict__ cpl_cnt, float* __restrict__ w_den,
         float* __restrict__ w_arr, int* __restrict__ hist)
{
    int e = blockIdx.x * 256 + threadIdx.x;
    if (e >= N_EDGES) return;
    int fmt = counters[0];
    bool t = fmt ? (((const uint8_t*)tie_raw)[e] != 0)
                 : (((const int*)tie_raw)[e] != 0);
    float w = 0.f;
    if (!t) {
        int c = ei[N_EDGES + e];
        if (cpl_cnt[c] > 0.f) {
            float X = fabsf(attr[(size_t)e * 10 + 1]);
            w = 1.f / sqrtf(X * X + 1e-6f);
            atomicAdd(&w_den[c], w);
            atomicAdd(&hist[c], 1);
        }
    }
    w_arr[e] = w;
}

// ---------------- dual CSR build ----------------
__global__ __launch_bounds__(SCAN_B)
void k_scan1(const int* __restrict__ hist, const float* __restrict__ cpl_cnt,
             int* __restrict__ excl, int* __restrict__ bsum,
             int* __restrict__ excl2, int* __restrict__ bsum2)
{
    __shared__ int s[SCAN_B];
    int t = threadIdx.x;
    int i = blockIdx.x * SCAN_B + t;
    int v = (i < N_NODES) ? hist[i] : 0;
    s[t] = v;
    __syncthreads();
    for (int o = 1; o < SCAN_B; o <<= 1) {
        int u = (t >= o) ? s[t - o] : 0;
        __syncthreads();
        s[t] += u;
        __syncthreads();
    }
    if (i < N_NODES) excl[i] = s[t] - v;
    if (t == SCAN_B - 1) bsum[blockIdx.x] = s[t];
    __syncthreads();
    int v2 = (i < N_NODES) ? (int)cpl_cnt[i] : 0;
    s[t] = v2;
    __syncthreads();
    for (int o = 1; o < SCAN_B; o <<= 1) {
        int u = (t >= o) ? s[t - o] : 0;
        __syncthreads();
        s[t] += u;
        __syncthreads();
    }
    if (i < N_NODES) excl2[i] = s[t] - v2;
    if (t == SCAN_B - 1) bsum2[blockIdx.x] = s[t];
}

__global__ void k_scan2(int* __restrict__ bsum, int* __restrict__ bsum2,
                        int* __restrict__ counters)
{
    const int NB = (N_NODES + SCAN_B - 1) / SCAN_B;
    if (threadIdx.x == 0) {
        int run = 0;
        for (int b = 0; b < NB; ++b) { int x = bsum[b]; bsum[b] = run; run += x; }
        counters[2] = run;
        int run2 = 0;
        for (int b = 0; b < NB; ++b) { int x = bsum2[b]; bsum2[b] = run2; run2 += x; }
        counters[3] = run2;
    }
}

__global__ __launch_bounds__(256)
void k_scan3(const int* __restrict__ excl, const int* __restrict__ bsum,
             const int* __restrict__ excl2, const int* __restrict__ bsum2,
             int* __restrict__ row_ptr, int* __restrict__ cursor,
             int* __restrict__ row_ptr2, int* __restrict__ cursor2,
             const int* __restrict__ counters,
             const float* __restrict__ cpl_cnt, const float* __restrict__ w_den,
             float* __restrict__ deg_inv, float* __restrict__ sumw)
{
    int i = blockIdx.x * 256 + threadIdx.x;
    if (i < N_NODES) {
        int v = excl[i] + bsum[i >> 8];
        row_ptr[i] = v;  cursor[i] = v;
        int v2 = excl2[i] + bsum2[i >> 8];
        row_ptr2[i] = v2; cursor2[i] = v2;
        deg_inv[i] = 1.f / fmaxf(cpl_cnt[i], 1.f);
        float wd = w_den[i];
        sumw[i] = wd / (wd + 1e-6f);
    }
    if (i == N_NODES) {
        row_ptr[N_NODES] = counters[2];
        row_ptr2[N_NODES] = counters[3];
    }
}

// blocks [0,EB_CONST): internal-edge CSR fill; [EB_CONST, +TB): tie-CSR fill
__global__ __launch_bounds__(256)
void k_fill(const int* __restrict__ ei, const float* __restrict__ w_arr,
            const float* __restrict__ w_den, int* __restrict__ cursor,
            int* __restrict__ csr_row, float* __restrict__ csr_w,
            const int* __restrict__ counters, const int* __restrict__ tie_list,
            const int* __restrict__ tie_row, const int* __restrict__ tie_col,
            int* __restrict__ cursor2, int* __restrict__ tcsr)
{
    int b = blockIdx.x;
    if (b < EB_CONST) {
        int e = b * 256 + threadIdx.x;
        if (e >= N_EDGES) return;
        float w = w_arr[e];
        if (w == 0.f) return;
        int c = ei[N_EDGES + e];
        int pos = atomicAdd(&cursor[c], 1);
        csr_row[pos] = ei[e];
        csr_w[pos] = w / (w_den[c] + 1e-6f);
    } else {
        int i = (b - EB_CONST) * 256 + threadIdx.x;
        int cnt = counters[1]; if (cnt > TIE_CAP) cnt = TIE_CAP;
        if (i < cnt) {
            int e = tie_list[i];
            int p1 = atomicAdd(&cursor2[tie_row[i]], 1); tcsr[p1] = e;
            int p2 = atomicAdd(&cursor2[tie_col[i]], 1); tcsr[p2] = e;
        }
    }
}

// ---------------- launch ----------------
extern "C" void kernel_launch(void* const* d_in, const int* in_sizes, int n_in,
                              void* d_out, int out_size, void* d_ws, size_t ws_size,
                              hipStream_t stream)
{
    const float* h     = (const float*)d_in[0];
    const float* e     = (const float*)d_in[1];
    const float* attr  = (const float*)d_in[2];
    const float* W_er1 = (const float*)d_in[3];
    const float* b_er1 = (const float*)d_in[4];
    const float* W_er2 = (const float*)d_in[5];
    const float* b_er2 = (const float*)d_in[6];
    const float* W_ih  = (const float*)d_in[7];
    const float* W_hh  = (const float*)d_in[8];
    const float* b_ih  = (const float*)d_in[9];
    const float* b_hh  = (const float*)d_in[10];
    const float* W_nn  = (const float*)d_in[11];
    const float* b_nn  = (const float*)d_in[12];
    const float* W_g1  = (const float*)d_in[13];
    const float* b_g1  = (const float*)d_in[14];
    const float* W_g2  = (const float*)d_in[15];
    const float* b_g2  = (const float*)d_in[16];
    const int*   ei    = (const int*)d_in[17];
    const void*  tie_raw = d_in[18];

    float* out_h = (float*)d_out;
    float* out_e = out_h + (size_t)N_NODES * HDIM;

    char* ws = (char*)d_ws;
    size_t off = 0;
    auto alloc = [&](size_t bytes) -> void* {
        void* p = ws + off;
        off = (off + bytes + 255) & ~(size_t)255;
        return p;
    };
    float* cpl_cnt = (float*)alloc((size_t)N_NODES * 4);
    float* w_den   = (float*)alloc((size_t)N_NODES * 4);
    int*   hist    = (int*)  alloc((size_t)N_NODES * 4);
    int*   counters= (int*)  alloc(256);  // [0]=fmt [1]=tie_cnt [2]=csr [3]=tcsr
    float* deg_inv = (float*)alloc((size_t)N_NODES * 4);
    float* sumw    = (float*)alloc((size_t)N_NODES * 4);
    float* w_arr   = (float*)alloc((size_t)N_EDGES * 4);
    int* tie_list  = (int*)alloc((size_t)TIE_CAP * 4);
    int* tie_row   = (int*)alloc((size_t)TIE_CAP * 4);
    int* tie_col   = (int*)alloc((size_t)TIE_CAP * 4);
    short* BTer1   = (short*)alloc((size_t)256 * 384 * 2);
    short* BTer2   = (short*)alloc((size_t)128 * 256 * 2);
    short* BTnn    = (short*)alloc((size_t)128 * 128 * 2);
    short* BTg1    = (short*)alloc((size_t)128 * 384 * 2);
    short* BTcomb  = (short*)alloc((size_t)256 * 256 * 2);
    short* BTihn   = (short*)alloc((size_t)128 * 128 * 2);
    short* BThhn   = (short*)alloc((size_t)128 * 128 * 2);
    uint16_t* h_bf = (uint16_t*)alloc((size_t)N_NODES * HDIM * 2);
    uint16_t* agg  = (uint16_t*)alloc((size_t)N_NODES * HDIM * 2);
    uint16_t* m_edge_bf = (uint16_t*)alloc((size_t)N_NODES * HDIM * 2);
    int* excl      = (int*)alloc((size_t)N_NODES * 4);
    int* excl2     = (int*)alloc((size_t)N_NODES * 4);
    int* bsum      = (int*)alloc(256 * 4);
    int* bsum2     = (int*)alloc(256 * 4);
    int* row_ptr   = (int*)alloc((size_t)(N_NODES + 1) * 4);
    int* row_ptr2  = (int*)alloc((size_t)(N_NODES + 1) * 4);
    int* cursor    = (int*)alloc((size_t)N_NODES * 4);
    int* cursor2   = (int*)alloc((size_t)N_NODES * 4);
    int* csr_row   = (int*)alloc((size_t)N_EDGES * 4);
    float* csr_w   = (float*)alloc((size_t)N_EDGES * 4);
    int* tcsr      = (int*)alloc((size_t)2 * TIE_CAP * 4);
    if (off > ws_size) return;

    const int GM_T = (TIE_CAP + 127) / 128;          // 344
    const int GM_N = (N_NODES + 127) / 128;          // 391
    const int NB   = (N_NODES + SCAN_B - 1) / SCAN_B;

    k_init<<<INIT_BLOCKS, 256, 0, stream>>>(
        e, out_e, h, out_h, h_bf, cpl_cnt, w_den, hist, counters,
        (const uint8_t*)tie_raw,
        W_er1, W_er2, W_nn, W_g1, W_ih, W_hh,
        BTer1, BTer2, BTnn, BTg1, BTcomb, BTihn, BThhn);
    k_tie<<<EB_CONST, 256, 0, stream>>>(tie_raw, counters, ei, cpl_cnt,
                                        counters + 1, tie_list, tie_row, tie_col);
    k_w<<<EB_CONST, 256, 0, stream>>>(tie_raw, counters, ei, attr, cpl_cnt,
                                      w_den, w_arr, hist);
    k_scan1<<<NB, SCAN_B, 0, stream>>>(hist, cpl_cnt, excl, bsum, excl2, bsum2);
    k_scan2<<<1, 64, 0, stream>>>(bsum, bsum2, counters);
    k_scan3<<<(N_NODES + 256) / 256, 256, 0, stream>>>(
        excl, bsum, excl2, bsum2, row_ptr, cursor, row_ptr2, cursor2,
        counters, cpl_cnt, w_den, deg_inv, sumw);
    k_fill<<<EB_CONST + TB_CONST, 256, 0, stream>>>(
        ei, w_arr, w_den, cursor, csr_row, csr_w,
        counters, tie_list, tie_row, tie_col, cursor2, tcsr);

    for (int it = 0; it < NITER; ++it) {
        const float* e_src = (it == 0) ? e : out_e;
        k_tie_fused<<<GM_T, 512, 0, stream>>>(
            e_src, out_e, counters, h_bf, tie_list, tie_row, tie_col,
            BTer1, BTer2, b_er1, b_er2);
        k_gather<<<(N_NODES + 3) / 4, 256, 0, stream>>>(
            row_ptr, csr_row, csr_w, h_bf, agg,
            row_ptr2, tcsr, out_e, deg_inv, m_edge_bf);
        k_node_mega<<<GM_N, 512, 0, stream>>>(
            m_edge_bf, agg, out_h, h_bf, cpl_cnt, sumw,
            BTnn, b_nn, BTg1, b_g1, W_g2, b_g2,
            BTcomb, BTihn, BThhn, b_ih, b_hh);
    }
}

// Round 15
// 846.990 us; speedup vs baseline: 1.1567x; 1.0075x over previous
//
#include <hip/hip_runtime.h>
#include <cstdint>

#define N_NODES 50000
#define N_EDGES 800000
#define HDIM    128
#define TIE_CAP 44000
#define NITER   2
#define SCAN_B  256
#define EB_CONST 3125            // N_EDGES/256
#define TB_CONST 172             // ceil(TIE_CAP/256)

typedef __attribute__((ext_vector_type(8))) short bf16x8;
typedef __attribute__((ext_vector_type(4))) float f32x4;

__device__ __forceinline__ uint32_t f2bf(float f) {
    uint32_t u = __builtin_bit_cast(uint32_t, f);
    return (u + 0x7fffu + ((u >> 16) & 1u)) >> 16;   // RNE
}
__device__ __forceinline__ float bf2f(uint32_t b) {
    return __builtin_bit_cast(float, b << 16);
}
__device__ __forceinline__ uint32_t comb2(uint32_t me, uint32_t mn, float g) {
    float a0 = bf2f(me & 0xffffu) + g * bf2f(mn & 0xffffu);
    float a1 = bf2f(me >> 16)     + g * bf2f(mn >> 16);
    return f2bf(a0) | (f2bf(a1) << 16);
}

// ---- LDS tiles: [128 rows][128 bf16] = 256B rows, byte ^= (row&7)<<4 ----

__device__ __forceinline__ void stage_a128(const float* __restrict__ base,
                                           const int* __restrict__ gidx,
                                           int m0, int Mlim, char* tile, int tid)
{
    const int c = tid & 15;
    #pragma unroll
    for (int p = 0; p < 4; ++p) {
        int row = p * 32 + (tid >> 4);
        int ar = m0 + row; if (ar >= Mlim) ar = Mlim - 1;
        long g = gidx ? gidx[ar] : ar;
        const float* s = base + g * HDIM + c * 4;
        float4 v0 = *(const float4*)s;
        float4 v1 = *(const float4*)(s + 64);
        uint2 w0 = make_uint2(f2bf(v0.x) | (f2bf(v0.y) << 16),
                              f2bf(v0.z) | (f2bf(v0.w) << 16));
        uint2 w1 = make_uint2(f2bf(v1.x) | (f2bf(v1.y) << 16),
                              f2bf(v1.z) | (f2bf(v1.w) << 16));
        int sw = (row & 7) << 4;
        *(uint2*)(tile + row * 256 + ((c * 8) ^ sw)) = w0;
        *(uint2*)(tile + row * 256 + ((c * 8 + 128) ^ sw)) = w1;
    }
}

__device__ __forceinline__ void stage_bf128(const uint16_t* __restrict__ base,
                                            const int* __restrict__ gidx,
                                            int m0, int Mlim, char* tile, int tid)
{
    const int c = tid & 15;
    #pragma unroll
    for (int p = 0; p < 4; ++p) {
        int row = p * 32 + (tid >> 4);
        int ar = m0 + row; if (ar >= Mlim) ar = Mlim - 1;
        long g = gidx ? gidx[ar] : ar;
        uint4 v = *(const uint4*)(base + g * HDIM + c * 8);
        *(uint4*)(tile + row * 256 + ((c * 16) ^ ((row & 7) << 4))) = v;
    }
}

__device__ __forceinline__ void stage_b128(const short* __restrict__ BT, int ldk,
                                           int n0, int k0, char* tile, int tid)
{
    const int c = tid & 15;
    #pragma unroll
    for (int p = 0; p < 4; ++p) {
        int n = p * 32 + (tid >> 4);
        uint4 v = *(const uint4*)&BT[(size_t)(n0 + n) * ldk + k0 + c * 8];
        *(uint4*)(tile + n * 256 + ((c * 16) ^ ((n & 7) << 4))) = v;
    }
}

// one K=128 chunk: 8 waves in 2(M)x4(N); wave does 64x32 via 16x16x32 MFMA
__device__ __forceinline__ void mfma128(const char* At, const char* Bt,
                                        int wr, int wc, int lane, f32x4 acc[4][2])
{
    #pragma unroll
    for (int ks = 0; ks < 4; ++ks) {
        int kb = ks * 64 + (lane >> 4) * 16;
        bf16x8 aF[4], bF[2];
        #pragma unroll
        for (int mi = 0; mi < 4; ++mi) {
            int row = wr * 64 + mi * 16 + (lane & 15);
            aF[mi] = *(const bf16x8*)(At + row * 256 + (kb ^ ((row & 7) << 4)));
        }
        #pragma unroll
        for (int ni = 0; ni < 2; ++ni) {
            int n = wc * 32 + ni * 16 + (lane & 15);
            bF[ni] = *(const bf16x8*)(Bt + n * 256 + (kb ^ ((n & 7) << 4)));
        }
        #pragma unroll
        for (int mi = 0; mi < 4; ++mi)
            #pragma unroll
            for (int ni = 0; ni < 2; ++ni)
                acc[mi][ni] = __builtin_amdgcn_mfma_f32_16x16x32_bf16(
                    aF[mi], bF[ni], acc[mi][ni], 0, 0, 0);
    }
}

// ---------------- fused tie-edge kernel (champion R11 form) -----------------
__global__ __launch_bounds__(512)
void k_tie_fused(const float* __restrict__ e_src, float* __restrict__ out_e,
                 const int* __restrict__ counters,
                 const uint16_t* __restrict__ h_bf,
                 const int* __restrict__ tie_list, const int* __restrict__ tie_row,
                 const int* __restrict__ tie_col,
                 const short* __restrict__ BTer1, const short* __restrict__ BTer2,
                 const float* __restrict__ b_er1, const float* __restrict__ b_er2)
{
    int cnt = counters[1]; if (cnt > TIE_CAP) cnt = TIE_CAP;
    const int m0 = blockIdx.x * 128;
    if (m0 >= cnt) return;

    __shared__ __align__(16) char At[32 * 1024];
    __shared__ __align__(16) char B0[32 * 1024];
    __shared__ __align__(16) char B1[32 * 1024];

    const int tid = threadIdx.x, lane = tid & 63;
    const int wid = tid >> 6, wr = wid >> 2, wc = wid & 3;

    f32x4 acc0[4][2] = {}, acc1[4][2] = {};
    #pragma unroll 1
    for (int c = 0; c < 3; ++c) {
        if (c == 0) stage_a128(e_src, tie_list, m0, cnt, At, tid);
        else        stage_bf128(h_bf, (c == 1) ? tie_row : tie_col, m0, cnt, At, tid);
        stage_b128(BTer1, 384, 0,   c * 128, B0, tid);
        stage_b128(BTer1, 384, 128, c * 128, B1, tid);
        __syncthreads();
        mfma128(At, B0, wr, wc, lane, acc0);
        mfma128(At, B1, wr, wc, lane, acc1);
        __syncthreads();
    }

    // epilogue1: relu(acc+b) -> bf16 C1 tiles (At = cols 0-127, B0 = 128-255)
    #pragma unroll
    for (int half = 0; half < 2; ++half) {
        char* Ct = half ? B0 : At;
        #pragma unroll
        for (int ni = 0; ni < 2; ++ni) {
            int col = wc * 32 + ni * 16 + (lane & 15);
            float bv = b_er1[half * 128 + col];
            #pragma unroll
            for (int mi = 0; mi < 4; ++mi)
                #pragma unroll
                for (int j = 0; j < 4; ++j) {
                    int rl = wr * 64 + mi * 16 + ((lane >> 4) << 2) + j;
                    float v = fmaxf((half ? acc1 : acc0)[mi][ni][j] + bv, 0.f);
                    *(uint16_t*)(Ct + rl * 256 + ((col * 2) ^ ((rl & 7) << 4))) =
                        (uint16_t)f2bf(v);
                }
        }
    }
    stage_b128(BTer2, 256, 0, 0, B1, tid);
    __syncthreads();
    f32x4 acc2[4][2] = {};
    mfma128(At, B1, wr, wc, lane, acc2);
    __syncthreads();
    stage_b128(BTer2, 256, 0, 128, B1, tid);
    __syncthreads();
    mfma128(B0, B1, wr, wc, lane, acc2);

    // epilogue2: out_e[tie] = e_src[tie] + eref
    int col0 = wc * 32 + (lane & 15);
    float bv0 = b_er2[col0], bv1 = b_er2[col0 + 16];
    #pragma unroll
    for (int mi = 0; mi < 4; ++mi) {
        #pragma unroll
        for (int j = 0; j < 4; ++j) {
            int i = m0 + wr * 64 + mi * 16 + ((lane >> 4) << 2) + j;
            if (i < cnt) {
                int e = tie_list[i];
                #pragma unroll
                for (int ni = 0; ni < 2; ++ni) {
                    int col = col0 + ni * 16;
                    size_t eb = (size_t)e * HDIM + col;
                    out_e[eb] = e_src[eb] + acc2[mi][ni][j] + (ni ? bv1 : bv0);
                }
            }
        }
    }
}

// -------- gather over COUPLING NODES ONLY: agg + m_edge per node ------------
__global__ __launch_bounds__(256)
void k_gather(const int* __restrict__ cpl_list, const int* __restrict__ counters,
              const int* __restrict__ row_ptr, const int* __restrict__ csr_row,
              const float* __restrict__ csr_w, const uint16_t* __restrict__ h_bf,
              uint16_t* __restrict__ agg,
              const int* __restrict__ row_ptr2, const int* __restrict__ tcsr,
              const float* __restrict__ out_e, const float* __restrict__ deg_inv,
              uint16_t* __restrict__ m_edge_bf)
{
    int idx = blockIdx.x * 4 + (threadIdx.x >> 6);
    if (idx >= counters[4]) return;
    int n = cpl_list[idx];
    int lane = threadIdx.x & 63;

    int s = row_ptr[n], t = row_ptr[n + 1];
    float a0 = 0.f, a1 = 0.f;
    for (int j = s; j < t; ++j) {
        int r = csr_row[j];
        float w = csr_w[j];
        uint32_t v = *(const uint32_t*)(h_bf + (size_t)r * HDIM + lane * 2);
        a0 += w * bf2f(v & 0xffffu);
        a1 += w * bf2f(v >> 16);
    }
    *(uint32_t*)(agg + (size_t)n * HDIM + lane * 2) = f2bf(a0) | (f2bf(a1) << 16);

    int s2 = row_ptr2[n], t2 = row_ptr2[n + 1];
    float b0 = 0.f, b1 = 0.f;
    for (int j = s2; j < t2; ++j) {
        int e = tcsr[j];
        float2 v = *(const float2*)(out_e + (size_t)e * HDIM + lane * 2);
        b0 += v.x; b1 += v.y;
    }
    float di = deg_inv[n];
    *(uint32_t*)(m_edge_bf + (size_t)n * HDIM + lane * 2) =
        f2bf(b0 * di) | (f2bf(b1 * di) << 16);
}

// ---- fused node kernel over COUPLING NODES (tiles gathered via cpl_list) ---
__global__ __launch_bounds__(512)
void k_node_mega(const int* __restrict__ cpl_list, const int* __restrict__ counters,
                 const uint16_t* __restrict__ m_edge_bf,
                 const uint16_t* __restrict__ agg,
                 float* __restrict__ out_h, uint16_t* __restrict__ h_bf,
                 const float* __restrict__ sumw,
                 const short* __restrict__ BTnn, const float* __restrict__ b_nn,
                 const short* __restrict__ BTg1, const float* __restrict__ b_g1,
                 const float* __restrict__ Wg2, const float* __restrict__ b_g2,
                 const short* __restrict__ BTcomb,
                 const short* __restrict__ BTihn, const short* __restrict__ BThhn,
                 const float* __restrict__ b_ih, const float* __restrict__ b_hh)
{
    const int ncpl = counters[4];
    const int m0 = blockIdx.x * 128;
    if (m0 >= ncpl) return;

    __shared__ __align__(16) char Tme[32 * 1024];   // m_edge tile; B buf in GRU
    __shared__ __align__(16) char Tmn[32 * 1024];   // agg -> m_node -> M
    __shared__ __align__(16) char Th [32 * 1024];
    __shared__ __align__(16) char Bt [32 * 1024];
    __shared__ float g_red[4][128];
    __shared__ float g_fin[128];
    __shared__ float sw_s[128];

    const int tid = threadIdx.x, lane = tid & 63;
    const int wid = tid >> 6, wr = wid >> 2, wc = wid & 3;

    stage_bf128(m_edge_bf, cpl_list, m0, ncpl, Tme, tid);
    stage_bf128(agg,       cpl_list, m0, ncpl, Tmn, tid);
    stage_bf128(h_bf,      cpl_list, m0, ncpl, Th,  tid);
    stage_b128(BTnn, 128, 0, 0, Bt, tid);
    if (tid < 128) {
        int i = m0 + tid; if (i >= ncpl) i = ncpl - 1;
        sw_s[tid] = sumw[cpl_list[i]];
    }
    __syncthreads();

    // ---- phase 0: m_node = agg @ W_nn + sumw*b_nn  -> bf16 into Tmn ----
    {
        f32x4 accM[4][2] = {};
        mfma128(Tmn, Bt, wr, wc, lane, accM);
        __syncthreads();
        #pragma unroll
        for (int ni = 0; ni < 2; ++ni) {
            int col = wc * 32 + ni * 16 + (lane & 15);
            float bv = b_nn[col];
            #pragma unroll
            for (int mi = 0; mi < 4; ++mi)
                #pragma unroll
                for (int j = 0; j < 4; ++j) {
                    int rl = wr * 64 + mi * 16 + ((lane >> 4) << 2) + j;
                    float v = accM[mi][ni][j] + sw_s[rl] * bv;
                    *(uint16_t*)(Tmn + rl * 256 + ((col * 2) ^ ((rl & 7) << 4))) =
                        (uint16_t)f2bf(v);
                }
        }
        __syncthreads();
    }

    // ---- gate GEMM: [me|mn|h](K=384) @ W_g1 ----
    f32x4 accG[4][2] = {};
    #pragma unroll 1
    for (int c = 0; c < 3; ++c) {
        const char* Ac = (c == 0) ? Tme : (c == 1) ? Tmn : Th;
        stage_b128(BTg1, 384, 0, c * 128, Bt, tid);
        __syncthreads();
        mfma128(Ac, Bt, wr, wc, lane, accG);
        __syncthreads();
    }
    {
        float bg[2], wg[2];
        #pragma unroll
        for (int ni = 0; ni < 2; ++ni) {
            int col = wc * 32 + ni * 16 + (lane & 15);
            bg[ni] = b_g1[col]; wg[ni] = Wg2[col];
        }
        #pragma unroll
        for (int mi = 0; mi < 4; ++mi)
            #pragma unroll
            for (int j = 0; j < 4; ++j) {
                float p = fmaxf(accG[mi][0][j] + bg[0], 0.f) * wg[0]
                        + fmaxf(accG[mi][1][j] + bg[1], 0.f) * wg[1];
                #pragma unroll
                for (int o = 8; o; o >>= 1) p += __shfl_xor(p, o);
                if ((lane & 15) == 0)
                    g_red[wc][wr * 64 + mi * 16 + ((lane >> 4) << 2) + j] = p;
            }
    }
    __syncthreads();
    if (tid < 128) {
        float t = g_red[0][tid] + g_red[1][tid] + g_red[2][tid] + g_red[3][tid]
                + b_g2[0];
        g_fin[tid] = 1.f / (1.f + __expf(-t));
    }
    __syncthreads();

    // M = me + g*mn (in place of Tmn); C0 staged alongside
    stage_b128(BTcomb, 256, 0, 0, Bt, tid);
    {
        const int c = tid & 15;
        #pragma unroll
        for (int p = 0; p < 4; ++p) {
            int row = p * 32 + (tid >> 4);
            float g = g_fin[row];
            int sw = (row & 7) << 4;
            #pragma unroll
            for (int hh = 0; hh < 2; ++hh) {
                int off = (c * 8 + hh * 128) ^ sw;
                uint2 me2 = *(uint2*)(Tme + row * 256 + off);
                uint2 mn2 = *(uint2*)(Tmn + row * 256 + off);
                *(uint2*)(Tmn + row * 256 + off) =
                    make_uint2(comb2(me2.x, mn2.x, g), comb2(me2.y, mn2.y, g));
            }
        }
    }
    __syncthreads();    // covers M-combine + C0 stage; Tme now DEAD -> B buffer

    // ---- GRU phases: ping-pong B between Bt and Tme ----
    f32x4 aR[4][2] = {}, aZ[4][2] = {}, aGI[4][2] = {}, aGH[4][2] = {};
    stage_b128(BTcomb, 256, 0, 128, Tme, tid);
    mfma128(Tmn, Bt, wr, wc, lane, aR);   __syncthreads();
    stage_b128(BTcomb, 256, 128, 0, Bt, tid);
    mfma128(Th, Tme, wr, wc, lane, aR);   __syncthreads();
    stage_b128(BTcomb, 256, 128, 128, Tme, tid);
    mfma128(Tmn, Bt, wr, wc, lane, aZ);   __syncthreads();
    stage_b128(BTihn, 128, 0, 0, Bt, tid);
    mfma128(Th, Tme, wr, wc, lane, aZ);   __syncthreads();
    stage_b128(BThhn, 128, 0, 0, Tme, tid);
    mfma128(Tmn, Bt, wr, wc, lane, aGI);  __syncthreads();
    mfma128(Th, Tme, wr, wc, lane, aGH);

    // ---- GRU epilogue (all rows are coupling nodes); maintains h_bf --------
    #pragma unroll
    for (int ni = 0; ni < 2; ++ni) {
        int col = wc * 32 + ni * 16 + (lane & 15);
        float br  = b_ih[col] + b_hh[col];
        float bz  = b_ih[128 + col] + b_hh[128 + col];
        float bin = b_ih[256 + col], bhn = b_hh[256 + col];
        #pragma unroll
        for (int mi = 0; mi < 4; ++mi)
            #pragma unroll
            for (int j = 0; j < 4; ++j) {
                int i = m0 + wr * 64 + mi * 16 + ((lane >> 4) << 2) + j;
                if (i < ncpl) {
                    int node = cpl_list[i];
                    float r = 1.f / (1.f + __expf(-(aR[mi][ni][j] + br)));
                    float z = 1.f / (1.f + __expf(-(aZ[mi][ni][j] + bz)));
                    float nn = tanhf(aGI[mi][ni][j] + bin + r * (aGH[mi][ni][j] + bhn));
                    size_t hb = (size_t)node * HDIM + col;
                    float hv = out_h[hb];
                    float hn = (1.f - z) * nn + z * hv;
                    out_h[hb] = hn;
                    h_bf[hb] = (uint16_t)f2bf(hn);
                }
            }
    }
}

// ---------------- k_init: block-partitioned prep (incl. e-copy) -------------
// [0,2048): e->out_e  [2048,2304): h->out_h+h_bf  [2304,2368): node zero
// [2368,2496): weights  2496: fmt detect
#define INIT_BLOCKS 2497

__global__ __launch_bounds__(256)
void k_init(const float* __restrict__ e, float* __restrict__ out_e,
            const float* __restrict__ h, float* __restrict__ out_h,
            uint16_t* __restrict__ h_bf,
            float* __restrict__ cpl_cnt, float* __restrict__ w_den,
            int* __restrict__ hist, int* __restrict__ counters,
            const uint8_t* __restrict__ tie_raw,
            const float* __restrict__ W_er1, const float* __restrict__ W_er2,
            const float* __restrict__ W_nn, const float* __restrict__ W_g1,
            const float* __restrict__ W_ih, const float* __restrict__ W_hh,
            short* __restrict__ BTer1, short* __restrict__ BTer2,
            short* __restrict__ BTnn, short* __restrict__ BTg1,
            short* __restrict__ BTcomb, short* __restrict__ BTihn,
            short* __restrict__ BThhn)
{
    const int b = blockIdx.x, t = threadIdx.x;
    if (b < 2048) {
        const float4* src = (const float4*)e;
        float4* dst = (float4*)out_e;
        for (int i = b * 256 + t; i < N_EDGES * HDIM / 4; i += 2048 * 256)
            dst[i] = src[i];
    } else if (b < 2304) {
        for (int i = (b - 2048) * 256 + t; i < N_NODES * HDIM / 4; i += 256 * 256) {
            float4 v = ((const float4*)h)[i];
            ((float4*)out_h)[i] = v;
            *(uint2*)(h_bf + (size_t)i * 4) =
                make_uint2(f2bf(v.x) | (f2bf(v.y) << 16),
                           f2bf(v.z) | (f2bf(v.w) << 16));
        }
    } else if (b < 2368) {
        for (int i = (b - 2304) * 256 + t; i < N_NODES; i += 64 * 256) {
            cpl_cnt[i] = 0.f; w_den[i] = 0.f; hist[i] = 0;
        }
    } else if (b < 2496) {
        for (int i = (b - 2368) * 256 + t; i < 384 * 256; i += 128 * 256) {
            {   int n = i / 384, k = i % 384;
                BTer1[i] = (short)f2bf(W_er1[(size_t)k * 256 + n]); }
            if (i < 128 * 256) {
                int n = i / 256, k = i % 256;
                BTer2[i] = (short)f2bf(W_er2[(size_t)k * 128 + n]); }
            if (i < 128 * 128) {
                int n = i / 128, k = i % 128;
                BTnn[i] = (short)f2bf(W_nn[(size_t)k * 128 + n]); }
            if (i < 128 * 384) {
                int n = i / 384, k = i % 384;
                BTg1[i] = (short)f2bf(W_g1[(size_t)k * 128 + n]); }
            if (i < 256 * 256) {
                int n = i >> 8, k = i & 255;
                float v = (k < 128) ? W_ih[n * 128 + k] : W_hh[n * 128 + (k - 128)];
                BTcomb[i] = (short)f2bf(v); }
            if (i < 128 * 128) {
                BTihn[i] = (short)f2bf(W_ih[256 * 128 + i]);
                BThhn[i] = (short)f2bf(W_hh[256 * 128 + i]); }
        }
    } else {
        if (t < 64) {
            int c = 0;
            for (int k = t; k < 4096; k += 64)
                if ((k & 3) && tie_raw[k]) c = 1;
            unsigned long long m = __ballot(c != 0);
            if (t == 0) {
                counters[0] = (m != 0ull) ? 1 : 0;
                counters[1] = 0; counters[2] = 0; counters[3] = 0;
                counters[4] = 0;
            }
        }
    }
}

// ---------------- tie classification (wave-aggregated compaction) -----------
__global__ __launch_bounds__(256)
void k_tie(const void* __restrict__ tie_raw, const int* __restrict__ counters,
           const int* __restrict__ ei, float* __restrict__ cpl_cnt,
           int* __restrict__ tie_cnt, int* __restrict__ tie_list,
           int* __restrict__ tie_row, int* __restrict__ tie_col)
{
    int e = blockIdx.x * 256 + threadIdx.x;
    int fmt = counters[0];
    bool t = false; int r = 0, c = 0;
    if (e < N_EDGES)
        t = fmt ? (((const uint8_t*)tie_raw)[e] != 0)
                : (((const int*)tie_raw)[e] != 0);
    if (t) {
        r = ei[e]; c = ei[N_EDGES + e];
        atomicAdd(&cpl_cnt[r], 1.f);
        atomicAdd(&cpl_cnt[c], 1.f);
    }
    unsigned long long m = __ballot(t);
    if (m == 0ull) return;
    int lane = threadIdx.x & 63;
    int first = __ffsll((unsigned long long)m) - 1;
    int base = 0;
    if (lane == first) base = atomicAdd(tie_cnt, __popcll(m));
    base = __shfl(base, first);
    if (t) {
        int idx = base + __popcll(m & ((1ull << lane) - 1ull));
        if (idx < TIE_CAP) { tie_list[idx] = e; tie_row[idx] = r; tie_col[idx] = c; }
    }
}

__global__ __launch_bounds__(256)
void k_w(const void* __restrict__ tie_raw, const int* __restrict__ counters,
         const int* __restrict__ ei, const float* __restrict__ attr,
         const float* __restrict__ cpl_cnt, float* __restrict__ w_den,
         float* __restrict__ w_arr, int* __restrict__ hist)
{
    int e = blockIdx.x * 256 + threadIdx.x;
    if (e >= N_EDGES) return;
    int fmt = counters[0];
    bool t = fmt ? (((const uint8_t*)tie_raw)[e] != 0)
                 : (((const int*)tie_raw)[e] != 0);
    float w = 0.f;
    if (!t) {
        int c = ei[N_EDGES + e];
        if (cpl_cnt[c] > 0.f) {
            float X = fabsf(attr[(size_t)e * 10 + 1]);
            w = 1.f / sqrtf(X * X + 1e-6f);
            atomicAdd(&w_den[c], w);
            atomicAdd(&hist[c], 1);
        }
    }
    w_arr[e] = w;
}

// ---------------- dual CSR build ----------------
__global__ __launch_bounds__(SCAN_B)
void k_scan1(const int* __restrict__ hist, const float* __restrict__ cpl_cnt,
             int* __restrict__ excl, int* __restrict__ bsum,
             int* __restrict__ excl2, int* __restrict__ bsum2)
{
    __shared__ int s[SCAN_B];
    int t = threadIdx.x;
    int i = blockIdx.x * SCAN_B + t;
    int v = (i < N_NODES) ? hist[i] : 0;
    s[t] = v;
    __syncthreads();
    for (int o = 1; o < SCAN_B; o <<= 1) {
        int u = (t >= o) ? s[t - o] : 0;
        __syncthreads();
        s[t] += u;
        __syncthreads();
    }
    if (i < N_NODES) excl[i] = s[t] - v;
    if (t == SCAN_B - 1) bsum[blockIdx.x] = s[t];
    __syncthreads();
    int v2 = (i < N_NODES) ? (int)cpl_cnt[i] : 0;
    s[t] = v2;
    __syncthreads();
    for (int o = 1; o < SCAN_B; o <<= 1) {
        int u = (t >= o) ? s[t - o] : 0;
        __syncthreads();
        s[t] += u;
        __syncthreads();
    }
    if (i < N_NODES) excl2[i] = s[t] - v2;
    if (t == SCAN_B - 1) bsum2[blockIdx.x] = s[t];
}

__global__ void k_scan2(int* __restrict__ bsum, int* __restrict__ bsum2,
                        int* __restrict__ counters)
{
    const int NB = (N_NODES + SCAN_B - 1) / SCAN_B;
    if (threadIdx.x == 0) {
        int run = 0;
        for (int b = 0; b < NB; ++b) { int x = bsum[b]; bsum[b] = run; run += x; }
        counters[2] = run;
        int run2 = 0;
        for (int b = 0; b < NB; ++b) { int x = bsum2[b]; bsum2[b] = run2; run2 += x; }
        counters[3] = run2;
    }
}

// scan3: row_ptrs, deg/sumw, and COUPLING-NODE LIST compaction
__global__ __launch_bounds__(256)
void k_scan3(const int* __restrict__ excl, const int* __restrict__ bsum,
             const int* __restrict__ excl2, const int* __restrict__ bsum2,
             int* __restrict__ row_ptr, int* __restrict__ cursor,
             int* __restrict__ row_ptr2, int* __restrict__ cursor2,
             int* __restrict__ counters,
             const float* __restrict__ cpl_cnt, const float* __restrict__ w_den,
             float* __restrict__ deg_inv, float* __restrict__ sumw,
             int* __restrict__ cpl_list)
{
    int i = blockIdx.x * 256 + threadIdx.x;
    bool in = (i < N_NODES);
    bool cpl = false;
    if (in) {
        int v = excl[i] + bsum[i >> 8];
        row_ptr[i] = v;  cursor[i] = v;
        int v2 = excl2[i] + bsum2[i >> 8];
        row_ptr2[i] = v2; cursor2[i] = v2;
        deg_inv[i] = 1.f / fmaxf(cpl_cnt[i], 1.f);
        float wd = w_den[i];
        sumw[i] = wd / (wd + 1e-6f);
        cpl = (cpl_cnt[i] > 0.f);
    }
    if (i == N_NODES) {
        row_ptr[N_NODES] = counters[2];
        row_ptr2[N_NODES] = counters[3];
    }
    // wave-aggregated compaction of coupling nodes
    unsigned long long m = __ballot(cpl);
    if (m) {
        int lane = threadIdx.x & 63;
        int first = __ffsll((unsigned long long)m) - 1;
        int base = 0;
        if (lane == first) base = atomicAdd(&counters[4], __popcll(m));
        base = __shfl(base, first);
        if (cpl)
            cpl_list[base + __popcll(m & ((1ull << lane) - 1ull))] = i;
    }
}

// blocks [0,EB_CONST): internal-edge CSR fill; [EB_CONST, +TB): tie-CSR fill
__global__ __launch_bounds__(256)
void k_fill(const int* __restrict__ ei, const float* __restrict__ w_arr,
            const float* __restrict__ w_den, int* __restrict__ cursor,
            int* __restrict__ csr_row, float* __restrict__ csr_w,
            const int* __restrict__ counters, const int* __restrict__ tie_list,
            const int* __restrict__ tie_row, const int* __restrict__ tie_col,
            int* __restrict__ cursor2, int* __restrict__ tcsr)
{
    int b = blockIdx.x;
    if (b < EB_CONST) {
        int e = b * 256 + threadIdx.x;
        if (e >= N_EDGES) return;
        float w = w_arr[e];
        if (w == 0.f) return;
        int c = ei[N_EDGES + e];
        int pos = atomicAdd(&cursor[c], 1);
        csr_row[pos] = ei[e];
        csr_w[pos] = w / (w_den[c] + 1e-6f);
    } else {
        int i = (b - EB_CONST) * 256 + threadIdx.x;
        int cnt = counters[1]; if (cnt > TIE_CAP) cnt = TIE_CAP;
        if (i < cnt) {
            int e = tie_list[i];
            int p1 = atomicAdd(&cursor2[tie_row[i]], 1); tcsr[p1] = e;
            int p2 = atomicAdd(&cursor2[tie_col[i]], 1); tcsr[p2] = e;
        }
    }
}

// ---------------- launch ----------------
extern "C" void kernel_launch(void* const* d_in, const int* in_sizes, int n_in,
                              void* d_out, int out_size, void* d_ws, size_t ws_size,
                              hipStream_t stream)
{
    const float* h     = (const float*)d_in[0];
    const float* e     = (const float*)d_in[1];
    const float* attr  = (const float*)d_in[2];
    const float* W_er1 = (const float*)d_in[3];
    const float* b_er1 = (const float*)d_in[4];
    const float* W_er2 = (const float*)d_in[5];
    const float* b_er2 = (const float*)d_in[6];
    const float* W_ih  = (const float*)d_in[7];
    const float* W_hh  = (const float*)d_in[8];
    const float* b_ih  = (const float*)d_in[9];
    const float* b_hh  = (const float*)d_in[10];
    const float* W_nn  = (const float*)d_in[11];
    const float* b_nn  = (const float*)d_in[12];
    const float* W_g1  = (const float*)d_in[13];
    const float* b_g1  = (const float*)d_in[14];
    const float* W_g2  = (const float*)d_in[15];
    const float* b_g2  = (const float*)d_in[16];
    const int*   ei    = (const int*)d_in[17];
    const void*  tie_raw = d_in[18];

    float* out_h = (float*)d_out;
    float* out_e = out_h + (size_t)N_NODES * HDIM;

    char* ws = (char*)d_ws;
    size_t off = 0;
    auto alloc = [&](size_t bytes) -> void* {
        void* p = ws + off;
        off = (off + bytes + 255) & ~(size_t)255;
        return p;
    };
    float* cpl_cnt = (float*)alloc((size_t)N_NODES * 4);
    float* w_den   = (float*)alloc((size_t)N_NODES * 4);
    int*   hist    = (int*)  alloc((size_t)N_NODES * 4);
    int*   counters= (int*)  alloc(256);  // [0]=fmt [1]=tie [2]=csr [3]=tcsr [4]=ncpl
    float* deg_inv = (float*)alloc((size_t)N_NODES * 4);
    float* sumw    = (float*)alloc((size_t)N_NODES * 4);
    float* w_arr   = (float*)alloc((size_t)N_EDGES * 4);
    int* tie_list  = (int*)alloc((size_t)TIE_CAP * 4);
    int* tie_row   = (int*)alloc((size_t)TIE_CAP * 4);
    int* tie_col   = (int*)alloc((size_t)TIE_CAP * 4);
    short* BTer1   = (short*)alloc((size_t)256 * 384 * 2);
    short* BTer2   = (short*)alloc((size_t)128 * 256 * 2);
    short* BTnn    = (short*)alloc((size_t)128 * 128 * 2);
    short* BTg1    = (short*)alloc((size_t)128 * 384 * 2);
    short* BTcomb  = (short*)alloc((size_t)256 * 256 * 2);
    short* BTihn   = (short*)alloc((size_t)128 * 128 * 2);
    short* BThhn   = (short*)alloc((size_t)128 * 128 * 2);
    uint16_t* h_bf = (uint16_t*)alloc((size_t)N_NODES * HDIM * 2);
    uint16_t* agg  = (uint16_t*)alloc((size_t)N_NODES * HDIM * 2);
    uint16_t* m_edge_bf = (uint16_t*)alloc((size_t)N_NODES * HDIM * 2);
    int* excl      = (int*)alloc((size_t)N_NODES * 4);
    int* excl2     = (int*)alloc((size_t)N_NODES * 4);
    int* bsum      = (int*)alloc(256 * 4);
    int* bsum2     = (int*)alloc(256 * 4);
    int* row_ptr   = (int*)alloc((size_t)(N_NODES + 1) * 4);
    int* row_ptr2  = (int*)alloc((size_t)(N_NODES + 1) * 4);
    int* cursor    = (int*)alloc((size_t)N_NODES * 4);
    int* cursor2   = (int*)alloc((size_t)N_NODES * 4);
    int* csr_row   = (int*)alloc((size_t)N_EDGES * 4);
    float* csr_w   = (float*)alloc((size_t)N_EDGES * 4);
    int* tcsr      = (int*)alloc((size_t)2 * TIE_CAP * 4);
    int* cpl_list  = (int*)alloc((size_t)N_NODES * 4);
    if (off > ws_size) return;

    const int GM_T = (TIE_CAP + 127) / 128;          // 344
    const int GM_N = (N_NODES + 127) / 128;          // 391 (upper bound; early-exit)
    const int NB   = (N_NODES + SCAN_B - 1) / SCAN_B;

    k_init<<<INIT_BLOCKS, 256, 0, stream>>>(
        e, out_e, h, out_h, h_bf, cpl_cnt, w_den, hist, counters,
        (const uint8_t*)tie_raw,
        W_er1, W_er2, W_nn, W_g1, W_ih, W_hh,
        BTer1, BTer2, BTnn, BTg1, BTcomb, BTihn, BThhn);
    k_tie<<<EB_CONST, 256, 0, stream>>>(tie_raw, counters, ei, cpl_cnt,
                                        counters + 1, tie_list, tie_row, tie_col);
    k_w<<<EB_CONST, 256, 0, stream>>>(tie_raw, counters, ei, attr, cpl_cnt,
                                      w_den, w_arr, hist);
    k_scan1<<<NB, SCAN_B, 0, stream>>>(hist, cpl_cnt, excl, bsum, excl2, bsum2);
    k_scan2<<<1, 64, 0, stream>>>(bsum, bsum2, counters);
    k_scan3<<<(N_NODES + 256) / 256, 256, 0, stream>>>(
        excl, bsum, excl2, bsum2, row_ptr, cursor, row_ptr2, cursor2,
        counters, cpl_cnt, w_den, deg_inv, sumw, cpl_list);
    k_fill<<<EB_CONST + TB_CONST, 256, 0, stream>>>(
        ei, w_arr, w_den, cursor, csr_row, csr_w,
        counters, tie_list, tie_row, tie_col, cursor2, tcsr);

    for (int it = 0; it < NITER; ++it) {
        const float* e_src = (it == 0) ? e : out_e;
        k_tie_fused<<<GM_T, 512, 0, stream>>>(
            e_src, out_e, counters, h_bf, tie_list, tie_row, tie_col,
            BTer1, BTer2, b_er1, b_er2);
        k_gather<<<(N_NODES + 3) / 4, 256, 0, stream>>>(
            cpl_list, counters, row_ptr, csr_row, csr_w, h_bf, agg,
            row_ptr2, tcsr, out_e, deg_inv, m_edge_bf);
        k_node_mega<<<GM_N, 512, 0, stream>>>(
            cpl_list, counters, m_edge_bf, agg, out_h, h_bf, sumw,
            BTnn, b_nn, BTg1, b_g1, W_g2, b_g2,
            BTcomb, BTihn, BThhn, b_ih, b_hh);
    }
}

// Round 16
// 806.404 us; speedup vs baseline: 1.2149x; 1.0503x over previous
//
#include <hip/hip_runtime.h>
#include <cstdint>

#define N_NODES 50000
#define N_EDGES 800000
#define HDIM    128
#define TIE_CAP 44000
#define NITER   2
#define SCAN_B  256
#define EB_CONST 3125            // N_EDGES/256
#define TB_CONST 172             // ceil(TIE_CAP/256)
#define BM_T    192              // tie tile rows  -> ceil(44000/192)=230 blocks
#define BM_N    160              // mega tile rows -> ~250 active blocks

typedef __attribute__((ext_vector_type(8))) short bf16x8;
typedef __attribute__((ext_vector_type(4))) float f32x4;

__device__ __forceinline__ uint32_t f2bf(float f) {
    uint32_t u = __builtin_bit_cast(uint32_t, f);
    return (u + 0x7fffu + ((u >> 16) & 1u)) >> 16;   // RNE
}
__device__ __forceinline__ float bf2f(uint32_t b) {
    return __builtin_bit_cast(float, b << 16);
}
__device__ __forceinline__ uint32_t comb2(uint32_t me, uint32_t mn, float g) {
    float a0 = bf2f(me & 0xffffu) + g * bf2f(mn & 0xffffu);
    float a1 = bf2f(me >> 16)     + g * bf2f(mn >> 16);
    return f2bf(a0) | (f2bf(a1) << 16);
}

// ---- LDS tiles: [R rows][128 bf16] = 256B rows, byte ^= (row&7)<<4 ----
// P = R/32 staging passes (256 threads stage 32 rows/pass)

template<int P>
__device__ __forceinline__ void stage_aP(const float* __restrict__ base,
                                         const int* __restrict__ gidx,
                                         int m0, int Mlim, char* tile, int tid)
{
    const int c = tid & 15;
    #pragma unroll
    for (int p = 0; p < P; ++p) {
        int row = p * 32 + (tid >> 4);
        int ar = m0 + row; if (ar >= Mlim) ar = Mlim - 1;
        long g = gidx ? gidx[ar] : ar;
        const float* s = base + g * HDIM + c * 4;
        float4 v0 = *(const float4*)s;
        float4 v1 = *(const float4*)(s + 64);
        uint2 w0 = make_uint2(f2bf(v0.x) | (f2bf(v0.y) << 16),
                              f2bf(v0.z) | (f2bf(v0.w) << 16));
        uint2 w1 = make_uint2(f2bf(v1.x) | (f2bf(v1.y) << 16),
                              f2bf(v1.z) | (f2bf(v1.w) << 16));
        int sw = (row & 7) << 4;
        *(uint2*)(tile + row * 256 + ((c * 8) ^ sw)) = w0;
        *(uint2*)(tile + row * 256 + ((c * 8 + 128) ^ sw)) = w1;
    }
}

template<int P>
__device__ __forceinline__ void stage_bfP(const uint16_t* __restrict__ base,
                                          const int* __restrict__ gidx,
                                          int m0, int Mlim, char* tile, int tid)
{
    const int c = tid & 15;
    #pragma unroll
    for (int p = 0; p < P; ++p) {
        int row = p * 32 + (tid >> 4);
        int ar = m0 + row; if (ar >= Mlim) ar = Mlim - 1;
        long g = gidx ? gidx[ar] : ar;
        uint4 v = *(const uint4*)(base + g * HDIM + c * 8);
        *(uint4*)(tile + row * 256 + ((c * 16) ^ ((row & 7) << 4))) = v;
    }
}

__device__ __forceinline__ void stage_b128(const short* __restrict__ BT, int ldk,
                                           int n0, int k0, char* tile, int tid)
{
    const int c = tid & 15;
    #pragma unroll
    for (int p = 0; p < 4; ++p) {
        int n = p * 32 + (tid >> 4);
        uint4 v = *(const uint4*)&BT[(size_t)(n0 + n) * ldk + k0 + c * 8];
        *(uint4*)(tile + n * 256 + ((c * 16) ^ ((n & 7) << 4))) = v;
    }
}

// one K=128 chunk; 8 waves 2(M)x4(N); wave covers MI*16 rows x 32 cols
template<int MI>
__device__ __forceinline__ void mfmaT(const char* At, const char* Bt,
                                      int wr, int wc, int lane, f32x4 acc[MI][2])
{
    #pragma unroll
    for (int ks = 0; ks < 4; ++ks) {
        int kb = ks * 64 + (lane >> 4) * 16;
        bf16x8 aF[MI], bF[2];
        #pragma unroll
        for (int mi = 0; mi < MI; ++mi) {
            int row = wr * (MI * 16) + mi * 16 + (lane & 15);
            aF[mi] = *(const bf16x8*)(At + row * 256 + (kb ^ ((row & 7) << 4)));
        }
        #pragma unroll
        for (int ni = 0; ni < 2; ++ni) {
            int n = wc * 32 + ni * 16 + (lane & 15);
            bF[ni] = *(const bf16x8*)(Bt + n * 256 + (kb ^ ((n & 7) << 4)));
        }
        #pragma unroll
        for (int mi = 0; mi < MI; ++mi)
            #pragma unroll
            for (int ni = 0; ni < 2; ++ni)
                acc[mi][ni] = __builtin_amdgcn_mfma_f32_16x16x32_bf16(
                    aF[mi], bF[ni], acc[mi][ni], 0, 0, 0);
    }
}

// ---------------- fused tie-edge kernel (BM=192, single block-wave) ---------
__global__ __launch_bounds__(512)
void k_tie_fused(const float* __restrict__ e_src, float* __restrict__ out_e,
                 const int* __restrict__ counters,
                 const uint16_t* __restrict__ h_bf,
                 const int* __restrict__ tie_list, const int* __restrict__ tie_row,
                 const int* __restrict__ tie_col,
                 const short* __restrict__ BTer1, const short* __restrict__ BTer2,
                 const float* __restrict__ b_er1, const float* __restrict__ b_er2)
{
    int cnt = counters[1]; if (cnt > TIE_CAP) cnt = TIE_CAP;
    const int m0 = blockIdx.x * BM_T;
    if (m0 >= cnt) return;

    __shared__ __align__(16) char At[BM_T * 256];   // 48 KB
    __shared__ __align__(16) char B0[32 * 1024];
    __shared__ __align__(16) char B1[32 * 1024];

    const int tid = threadIdx.x, lane = tid & 63;
    const int wid = tid >> 6, wr = wid >> 2, wc = wid & 3;
    const int MI = BM_T / 32;   // 6

    f32x4 acc0[MI][2] = {}, acc1[MI][2] = {};
    #pragma unroll 1
    for (int c = 0; c < 3; ++c) {
        if (c == 0) stage_aP<BM_T/32>(e_src, tie_list, m0, cnt, At, tid);
        else        stage_bfP<BM_T/32>(h_bf, (c == 1) ? tie_row : tie_col, m0, cnt, At, tid);
        stage_b128(BTer1, 384, 0,   c * 128, B0, tid);
        stage_b128(BTer1, 384, 128, c * 128, B1, tid);
        __syncthreads();
        mfmaT<MI>(At, B0, wr, wc, lane, acc0);
        mfmaT<MI>(At, B1, wr, wc, lane, acc1);
        __syncthreads();
    }

    // epilogue1: relu(acc+b) -> bf16 C1: cols 0-127 -> At rows, 128-255 -> B0.
    // NOTE: At is 192 rows (48KB); C1a needs 192x128bf16 = 48KB exactly.
    //       B0 holds C1b 192 rows? B0 is 32KB = 128 rows -> NOT enough.
    // Fix: C1b (cols 128-255) lives in B0 for rows 0-127 and B1 for rows 128-191.
    #pragma unroll
    for (int half = 0; half < 2; ++half) {
        #pragma unroll
        for (int ni = 0; ni < 2; ++ni) {
            int col = wc * 32 + ni * 16 + (lane & 15);
            float bv = b_er1[half * 128 + col];
            #pragma unroll
            for (int mi = 0; mi < MI; ++mi)
                #pragma unroll
                for (int j = 0; j < 4; ++j) {
                    int rl = wr * (MI * 16) + mi * 16 + ((lane >> 4) << 2) + j;
                    float v = fmaxf((half ? acc1 : acc0)[mi][ni][j] + bv, 0.f);
                    char* Ct; int rr;
                    if (half == 0) { Ct = At; rr = rl; }
                    else if (rl < 128) { Ct = B0; rr = rl; }
                    else { Ct = B1; rr = rl - 128; }
                    *(uint16_t*)(Ct + rr * 256 + ((col * 2) ^ ((rr & 7) << 4))) =
                        (uint16_t)f2bf(v);
                }
        }
    }
    __syncthreads();

    // L2: acc2 = C1a @ B2a + C1b @ B2b.  B2 staged into B1's upper region?
    // B1 rows 0-63 hold C1b rows 128-191 (64 rows = 16KB). B2 tiles are 128
    // n-rows x 128 k = 32KB each; stage B2a into B1+16KB? Not enough space.
    // Instead: read BTer2 fragments DIRECTLY from global (L2-resident, only
    // 2 reads of 32KB per block; small phase — acceptable).
    f32x4 acc2[MI][2] = {};
    {
        // B fragment from global: wave covers n = wc*32 + ni*16 + (lane&15),
        // k chunk kb = ks*64 + (lane>>4)*16 within K-half c2*128.
        #pragma unroll 1
        for (int c2 = 0; c2 < 2; ++c2) {
            #pragma unroll
            for (int ks = 0; ks < 4; ++ks) {
                int kb = c2 * 128 + ks * 32 + (lane >> 4) * 8;
                bf16x8 bF[2];
                #pragma unroll
                for (int ni = 0; ni < 2; ++ni) {
                    int n = wc * 32 + ni * 16 + (lane & 15);
                    bF[ni] = *(const bf16x8*)&BTer2[(size_t)n * 256 + kb];
                }
                int kbl = ks * 64 + (lane >> 4) * 16;
                #pragma unroll
                for (int mi = 0; mi < MI; ++mi) {
                    int rl = wr * (MI * 16) + mi * 16 + (lane & 15);
                    const char* Ct; int rr;
                    if (c2 == 0) { Ct = At; rr = rl; }
                    else if (rl < 128) { Ct = B0; rr = rl; }
                    else { Ct = B1; rr = rl - 128; }
                    bf16x8 aF = *(const bf16x8*)(Ct + rr * 256 + (kbl ^ ((rr & 7) << 4)));
                    #pragma unroll
                    for (int ni = 0; ni < 2; ++ni)
                        acc2[mi][ni] = __builtin_amdgcn_mfma_f32_16x16x32_bf16(
                            aF, bF[ni], acc2[mi][ni], 0, 0, 0);
                }
            }
        }
    }

    // epilogue2: out_e[tie] = e_src[tie] + eref
    int col0 = wc * 32 + (lane & 15);
    float bv0 = b_er2[col0], bv1 = b_er2[col0 + 16];
    #pragma unroll
    for (int mi = 0; mi < MI; ++mi) {
        #pragma unroll
        for (int j = 0; j < 4; ++j) {
            int i = m0 + wr * (MI * 16) + mi * 16 + ((lane >> 4) << 2) + j;
            if (i < cnt) {
                int e = tie_list[i];
                #pragma unroll
                for (int ni = 0; ni < 2; ++ni) {
                    int col = col0 + ni * 16;
                    size_t eb = (size_t)e * HDIM + col;
                    out_e[eb] = e_src[eb] + acc2[mi][ni][j] + (ni ? bv1 : bv0);
                }
            }
        }
    }
}

// -------- gather over COUPLING NODES ONLY: agg + m_edge per node ------------
__global__ __launch_bounds__(256)
void k_gather(const int* __restrict__ cpl_list, const int* __restrict__ counters,
              const int* __restrict__ row_ptr, const int* __restrict__ csr_row,
              const float* __restrict__ csr_w, const uint16_t* __restrict__ h_bf,
              uint16_t* __restrict__ agg,
              const int* __restrict__ row_ptr2, const int* __restrict__ tcsr,
              const float* __restrict__ out_e, const float* __restrict__ deg_inv,
              uint16_t* __restrict__ m_edge_bf)
{
    int idx = blockIdx.x * 4 + (threadIdx.x >> 6);
    if (idx >= counters[4]) return;
    int n = cpl_list[idx];
    int lane = threadIdx.x & 63;

    int s = row_ptr[n], t = row_ptr[n + 1];
    float a0 = 0.f, a1 = 0.f;
    for (int j = s; j < t; ++j) {
        int r = csr_row[j];
        float w = csr_w[j];
        uint32_t v = *(const uint32_t*)(h_bf + (size_t)r * HDIM + lane * 2);
        a0 += w * bf2f(v & 0xffffu);
        a1 += w * bf2f(v >> 16);
    }
    *(uint32_t*)(agg + (size_t)n * HDIM + lane * 2) = f2bf(a0) | (f2bf(a1) << 16);

    int s2 = row_ptr2[n], t2 = row_ptr2[n + 1];
    float b0 = 0.f, b1 = 0.f;
    for (int j = s2; j < t2; ++j) {
        int e = tcsr[j];
        float2 v = *(const float2*)(out_e + (size_t)e * HDIM + lane * 2);
        b0 += v.x; b1 += v.y;
    }
    float di = deg_inv[n];
    *(uint32_t*)(m_edge_bf + (size_t)n * HDIM + lane * 2) =
        f2bf(b0 * di) | (f2bf(b1 * di) << 16);
}

// ---- fused node kernel over COUPLING NODES (BM=160, single block-wave) -----
__global__ __launch_bounds__(512)
void k_node_mega(const int* __restrict__ cpl_list, const int* __restrict__ counters,
                 const uint16_t* __restrict__ m_edge_bf,
                 const uint16_t* __restrict__ agg,
                 float* __restrict__ out_h, uint16_t* __restrict__ h_bf,
                 const float* __restrict__ sumw,
                 const short* __restrict__ BTnn, const float* __restrict__ b_nn,
                 const short* __restrict__ BTg1, const float* __restrict__ b_g1,
                 const float* __restrict__ Wg2, const float* __restrict__ b_g2,
                 const short* __restrict__ BTcomb,
                 const short* __restrict__ BTihn, const short* __restrict__ BThhn,
                 const float* __restrict__ b_ih, const float* __restrict__ b_hh)
{
    const int ncpl = counters[4];
    const int m0 = blockIdx.x * BM_N;
    if (m0 >= ncpl) return;

    __shared__ __align__(16) char Tme[BM_N * 256];   // 40 KB; B buf in GRU
    __shared__ __align__(16) char Tmn[BM_N * 256];   // agg -> m_node -> M
    __shared__ __align__(16) char Th [BM_N * 256];
    __shared__ __align__(16) char Bt [32 * 1024];
    __shared__ float g_red[4][BM_N];
    __shared__ float g_fin[BM_N];
    __shared__ float sw_s[BM_N];

    const int tid = threadIdx.x, lane = tid & 63;
    const int wid = tid >> 6, wr = wid >> 2, wc = wid & 3;
    const int MI = BM_N / 32;   // 5

    stage_bfP<BM_N/32>(m_edge_bf, cpl_list, m0, ncpl, Tme, tid);
    stage_bfP<BM_N/32>(agg,       cpl_list, m0, ncpl, Tmn, tid);
    stage_bfP<BM_N/32>(h_bf,      cpl_list, m0, ncpl, Th,  tid);
    stage_b128(BTnn, 128, 0, 0, Bt, tid);
    for (int i2 = tid; i2 < BM_N; i2 += 512) {
        int i = m0 + i2; if (i >= ncpl) i = ncpl - 1;
        sw_s[i2] = sumw[cpl_list[i]];
    }
    __syncthreads();

    // ---- phase 0: m_node = agg @ W_nn + sumw*b_nn  -> bf16 into Tmn ----
    {
        f32x4 accM[MI][2] = {};
        mfmaT<MI>(Tmn, Bt, wr, wc, lane, accM);
        __syncthreads();
        #pragma unroll
        for (int ni = 0; ni < 2; ++ni) {
            int col = wc * 32 + ni * 16 + (lane & 15);
            float bv = b_nn[col];
            #pragma unroll
            for (int mi = 0; mi < MI; ++mi)
                #pragma unroll
                for (int j = 0; j < 4; ++j) {
                    int rl = wr * (MI * 16) + mi * 16 + ((lane >> 4) << 2) + j;
                    float v = accM[mi][ni][j] + sw_s[rl] * bv;
                    *(uint16_t*)(Tmn + rl * 256 + ((col * 2) ^ ((rl & 7) << 4))) =
                        (uint16_t)f2bf(v);
                }
        }
        __syncthreads();
    }

    // ---- gate GEMM: [me|mn|h](K=384) @ W_g1 ----
    {
        f32x4 accG[MI][2] = {};
        #pragma unroll 1
        for (int c = 0; c < 3; ++c) {
            const char* Ac = (c == 0) ? Tme : (c == 1) ? Tmn : Th;
            stage_b128(BTg1, 384, 0, c * 128, Bt, tid);
            __syncthreads();
            mfmaT<MI>(Ac, Bt, wr, wc, lane, accG);
            __syncthreads();
        }
        float bg[2], wg[2];
        #pragma unroll
        for (int ni = 0; ni < 2; ++ni) {
            int col = wc * 32 + ni * 16 + (lane & 15);
            bg[ni] = b_g1[col]; wg[ni] = Wg2[col];
        }
        #pragma unroll
        for (int mi = 0; mi < MI; ++mi)
            #pragma unroll
            for (int j = 0; j < 4; ++j) {
                float p = fmaxf(accG[mi][0][j] + bg[0], 0.f) * wg[0]
                        + fmaxf(accG[mi][1][j] + bg[1], 0.f) * wg[1];
                #pragma unroll
                for (int o = 8; o; o >>= 1) p += __shfl_xor(p, o);
                if ((lane & 15) == 0)
                    g_red[wc][wr * (MI * 16) + mi * 16 + ((lane >> 4) << 2) + j] = p;
            }
    }
    __syncthreads();
    for (int i2 = tid; i2 < BM_N; i2 += 512) {
        float t = g_red[0][i2] + g_red[1][i2] + g_red[2][i2] + g_red[3][i2]
                + b_g2[0];
        g_fin[i2] = 1.f / (1.f + __expf(-t));
    }
    __syncthreads();

    // M = me + g*mn (in place of Tmn); C0 staged alongside
    stage_b128(BTcomb, 256, 0, 0, Bt, tid);
    {
        const int c = tid & 15;
        #pragma unroll
        for (int p = 0; p < BM_N / 32; ++p) {
            int row = p * 32 + (tid >> 4);
            float g = g_fin[row];
            int sw = (row & 7) << 4;
            #pragma unroll
            for (int hh = 0; hh < 2; ++hh) {
                int off = (c * 8 + hh * 128) ^ sw;
                uint2 me2 = *(uint2*)(Tme + row * 256 + off);
                uint2 mn2 = *(uint2*)(Tmn + row * 256 + off);
                *(uint2*)(Tmn + row * 256 + off) =
                    make_uint2(comb2(me2.x, mn2.x, g), comb2(me2.y, mn2.y, g));
            }
        }
    }
    __syncthreads();    // covers M-combine + C0 stage; Tme now DEAD -> B buffer

    // ---- GRU phases: ping-pong B between Bt and Tme ----
    f32x4 aR[MI][2] = {}, aZ[MI][2] = {}, aGI[MI][2] = {}, aGH[MI][2] = {};
    stage_b128(BTcomb, 256, 0, 128, Tme, tid);
    mfmaT<MI>(Tmn, Bt, wr, wc, lane, aR);   __syncthreads();
    stage_b128(BTcomb, 256, 128, 0, Bt, tid);
    mfmaT<MI>(Th, Tme, wr, wc, lane, aR);   __syncthreads();
    stage_b128(BTcomb, 256, 128, 128, Tme, tid);
    mfmaT<MI>(Tmn, Bt, wr, wc, lane, aZ);   __syncthreads();
    stage_b128(BTihn, 128, 0, 0, Bt, tid);
    mfmaT<MI>(Th, Tme, wr, wc, lane, aZ);   __syncthreads();
    stage_b128(BThhn, 128, 0, 0, Tme, tid);
    mfmaT<MI>(Tmn, Bt, wr, wc, lane, aGI);  __syncthreads();
    mfmaT<MI>(Th, Tme, wr, wc, lane, aGH);

    // ---- GRU epilogue (all rows are coupling nodes); maintains h_bf --------
    #pragma unroll
    for (int ni = 0; ni < 2; ++ni) {
        int col = wc * 32 + ni * 16 + (lane & 15);
        float br  = b_ih[col] + b_hh[col];
        float bz  = b_ih[128 + col] + b_hh[128 + col];
        float bin = b_ih[256 + col], bhn = b_hh[256 + col];
        #pragma unroll
        for (int mi = 0; mi < MI; ++mi)
            #pragma unroll
            for (int j = 0; j < 4; ++j) {
                int i = m0 + wr * (MI * 16) + mi * 16 + ((lane >> 4) << 2) + j;
                if (i < ncpl) {
                    int node = cpl_list[i];
                    float r = 1.f / (1.f + __expf(-(aR[mi][ni][j] + br)));
                    float z = 1.f / (1.f + __expf(-(aZ[mi][ni][j] + bz)));
                    float nn = tanhf(aGI[mi][ni][j] + bin + r * (aGH[mi][ni][j] + bhn));
                    size_t hb = (size_t)node * HDIM + col;
                    float hv = out_h[hb];
                    float hn = (1.f - z) * nn + z * hv;
                    out_h[hb] = hn;
                    h_bf[hb] = (uint16_t)f2bf(hn);
                }
            }
    }
}

// ---------------- k_init: block-partitioned prep (incl. e-copy) -------------
#define INIT_BLOCKS 2497

__global__ __launch_bounds__(256)
void k_init(const float* __restrict__ e, float* __restrict__ out_e,
            const float* __restrict__ h, float* __restrict__ out_h,
            uint16_t* __restrict__ h_bf,
            float* __restrict__ cpl_cnt, float* __restrict__ w_den,
            int* __restrict__ hist, int* __restrict__ counters,
            const uint8_t* __restrict__ tie_raw,
            const float* __restrict__ W_er1, const float* __restrict__ W_er2,
            const float* __restrict__ W_nn, const float* __restrict__ W_g1,
            const float* __restrict__ W_ih, const float* __restrict__ W_hh,
            short* __restrict__ BTer1, short* __restrict__ BTer2,
            short* __restrict__ BTnn, short* __restrict__ BTg1,
            short* __restrict__ BTcomb, short* __restrict__ BTihn,
            short* __restrict__ BThhn)
{
    const int b = blockIdx.x, t = threadIdx.x;
    if (b < 2048) {
        const float4* src = (const float4*)e;
        float4* dst = (float4*)out_e;
        for (int i = b * 256 + t; i < N_EDGES * HDIM / 4; i += 2048 * 256)
            dst[i] = src[i];
    } else if (b < 2304) {
        for (int i = (b - 2048) * 256 + t; i < N_NODES * HDIM / 4; i += 256 * 256) {
            float4 v = ((const float4*)h)[i];
            ((float4*)out_h)[i] = v;
            *(uint2*)(h_bf + (size_t)i * 4) =
                make_uint2(f2bf(v.x) | (f2bf(v.y) << 16),
                           f2bf(v.z) | (f2bf(v.w) << 16));
        }
    } else if (b < 2368) {
        for (int i = (b - 2304) * 256 + t; i < N_NODES; i += 64 * 256) {
            cpl_cnt[i] = 0.f; w_den[i] = 0.f; hist[i] = 0;
        }
    } else if (b < 2496) {
        for (int i = (b - 2368) * 256 + t; i < 384 * 256; i += 128 * 256) {
            {   int n = i / 384, k = i % 384;
                BTer1[i] = (short)f2bf(W_er1[(size_t)k * 256 + n]); }
            if (i < 128 * 256) {
                int n = i / 256, k = i % 256;
                BTer2[i] = (short)f2bf(W_er2[(size_t)k * 128 + n]); }
            if (i < 128 * 128) {
                int n = i / 128, k = i % 128;
                BTnn[i] = (short)f2bf(W_nn[(size_t)k * 128 + n]); }
            if (i < 128 * 384) {
                int n = i / 384, k = i % 384;
                BTg1[i] = (short)f2bf(W_g1[(size_t)k * 128 + n]); }
            if (i < 256 * 256) {
                int n = i >> 8, k = i & 255;
                float v = (k < 128) ? W_ih[n * 128 + k] : W_hh[n * 128 + (k - 128)];
                BTcomb[i] = (short)f2bf(v); }
            if (i < 128 * 128) {
                BTihn[i] = (short)f2bf(W_ih[256 * 128 + i]);
                BThhn[i] = (short)f2bf(W_hh[256 * 128 + i]); }
        }
    } else {
        if (t < 64) {
            int c = 0;
            for (int k = t; k < 4096; k += 64)
                if ((k & 3) && tie_raw[k]) c = 1;
            unsigned long long m = __ballot(c != 0);
            if (t == 0) {
                counters[0] = (m != 0ull) ? 1 : 0;
                counters[1] = 0; counters[2] = 0; counters[3] = 0;
                counters[4] = 0;
            }
        }
    }
}

// ---------------- tie classification (wave-aggregated compaction) -----------
__global__ __launch_bounds__(256)
void k_tie(const void* __restrict__ tie_raw, const int* __restrict__ counters,
           const int* __restrict__ ei, float* __restrict__ cpl_cnt,
           int* __restrict__ tie_cnt, int* __restrict__ tie_list,
           int* __restrict__ tie_row, int* __restrict__ tie_col)
{
    int e = blockIdx.x * 256 + threadIdx.x;
    int fmt = counters[0];
    bool t = false; int r = 0, c = 0;
    if (e < N_EDGES)
        t = fmt ? (((const uint8_t*)tie_raw)[e] != 0)
                : (((const int*)tie_raw)[e] != 0);
    if (t) {
        r = ei[e]; c = ei[N_EDGES + e];
        atomicAdd(&cpl_cnt[r], 1.f);
        atomicAdd(&cpl_cnt[c], 1.f);
    }
    unsigned long long m = __ballot(t);
    if (m == 0ull) return;
    int lane = threadIdx.x & 63;
    int first = __ffsll((unsigned long long)m) - 1;
    int base = 0;
    if (lane == first) base = atomicAdd(tie_cnt, __popcll(m));
    base = __shfl(base, first);
    if (t) {
        int idx = base + __popcll(m & ((1ull << lane) - 1ull));
        if (idx < TIE_CAP) { tie_list[idx] = e; tie_row[idx] = r; tie_col[idx] = c; }
    }
}

__global__ __launch_bounds__(256)
void k_w(const void* __restrict__ tie_raw, const int* __restrict__ counters,
         const int* __restrict__ ei, const float* __restrict__ attr,
         const float* __restrict__ cpl_cnt, float* __restrict__ w_den,
         float* __restrict__ w_arr, int* __restrict__ hist)
{
    int e = blockIdx.x * 256 + threadIdx.x;
    if (e >= N_EDGES) return;
    int fmt = counters[0];
    bool t = fmt ? (((const uint8_t*)tie_raw)[e] != 0)
                 : (((const int*)tie_raw)[e] != 0);
    float w = 0.f;
    if (!t) {
        int c = ei[N_EDGES + e];
        if (cpl_cnt[c] > 0.f) {
            float X = fabsf(attr[(size_t)e * 10 + 1]);
            w = 1.f / sqrtf(X * X + 1e-6f);
            atomicAdd(&w_den[c], w);
            atomicAdd(&hist[c], 1);
        }
    }
    w_arr[e] = w;
}

// ---------------- dual CSR build ----------------
__global__ __launch_bounds__(SCAN_B)
void k_scan1(const int* __restrict__ hist, const float* __restrict__ cpl_cnt,
             int* __restrict__ excl, int* __restrict__ bsum,
             int* __restrict__ excl2, int* __restrict__ bsum2)
{
    __shared__ int s[SCAN_B];
    int t = threadIdx.x;
    int i = blockIdx.x * SCAN_B + t;
    int v = (i < N_NODES) ? hist[i] : 0;
    s[t] = v;
    __syncthreads();
    for (int o = 1; o < SCAN_B; o <<= 1) {
        int u = (t >= o) ? s[t - o] : 0;
        __syncthreads();
        s[t] += u;
        __syncthreads();
    }
    if (i < N_NODES) excl[i] = s[t] - v;
    if (t == SCAN_B - 1) bsum[blockIdx.x] = s[t];
    __syncthreads();
    int v2 = (i < N_NODES) ? (int)cpl_cnt[i] : 0;
    s[t] = v2;
    __syncthreads();
    for (int o = 1; o < SCAN_B; o <<= 1) {
        int u = (t >= o) ? s[t - o] : 0;
        __syncthreads();
        s[t] += u;
        __syncthreads();
    }
    if (i < N_NODES) excl2[i] = s[t] - v2;
    if (t == SCAN_B - 1) bsum2[blockIdx.x] = s[t];
}

__global__ void k_scan2(int* __restrict__ bsum, int* __restrict__ bsum2,
                        int* __restrict__ counters)
{
    const int NB = (N_NODES + SCAN_B - 1) / SCAN_B;
    if (threadIdx.x == 0) {
        int run = 0;
        for (int b = 0; b < NB; ++b) { int x = bsum[b]; bsum[b] = run; run += x; }
        counters[2] = run;
        int run2 = 0;
        for (int b = 0; b < NB; ++b) { int x = bsum2[b]; bsum2[b] = run2; run2 += x; }
        counters[3] = run2;
    }
}

__global__ __launch_bounds__(256)
void k_scan3(const int* __restrict__ excl, const int* __restrict__ bsum,
             const int* __restrict__ excl2, const int* __restrict__ bsum2,
             int* __restrict__ row_ptr, int* __restrict__ cursor,
             int* __restrict__ row_ptr2, int* __restrict__ cursor2,
             int* __restrict__ counters,
             const float* __restrict__ cpl_cnt, const float* __restrict__ w_den,
             float* __restrict__ deg_inv, float* __restrict__ sumw,
             int* __restrict__ cpl_list)
{
    int i = blockIdx.x * 256 + threadIdx.x;
    bool cpl = false;
    if (i < N_NODES) {
        int v = excl[i] + bsum[i >> 8];
        row_ptr[i] = v;  cursor[i] = v;
        int v2 = excl2[i] + bsum2[i >> 8];
        row_ptr2[i] = v2; cursor2[i] = v2;
        deg_inv[i] = 1.f / fmaxf(cpl_cnt[i], 1.f);
        float wd = w_den[i];
        sumw[i] = wd / (wd + 1e-6f);
        cpl = (cpl_cnt[i] > 0.f);
    }
    if (i == N_NODES) {
        row_ptr[N_NODES] = counters[2];
        row_ptr2[N_NODES] = counters[3];
    }
    unsigned long long m = __ballot(cpl);
    if (m) {
        int lane = threadIdx.x & 63;
        int first = __ffsll((unsigned long long)m) - 1;
        int base = 0;
        if (lane == first) base = atomicAdd(&counters[4], __popcll(m));
        base = __shfl(base, first);
        if (cpl)
            cpl_list[base + __popcll(m & ((1ull << lane) - 1ull))] = i;
    }
}

__global__ __launch_bounds__(256)
void k_fill(const int* __restrict__ ei, const float* __restrict__ w_arr,
            const float* __restrict__ w_den, int* __restrict__ cursor,
            int* __restrict__ csr_row, float* __restrict__ csr_w,
            const int* __restrict__ counters, const int* __restrict__ tie_list,
            const int* __restrict__ tie_row, const int* __restrict__ tie_col,
            int* __restrict__ cursor2, int* __restrict__ tcsr)
{
    int b = blockIdx.x;
    if (b < EB_CONST) {
        int e = b * 256 + threadIdx.x;
        if (e >= N_EDGES) return;
        float w = w_arr[e];
        if (w == 0.f) return;
        int c = ei[N_EDGES + e];
        int pos = atomicAdd(&cursor[c], 1);
        csr_row[pos] = ei[e];
        csr_w[pos] = w / (w_den[c] + 1e-6f);
    } else {
        int i = (b - EB_CONST) * 256 + threadIdx.x;
        int cnt = counters[1]; if (cnt > TIE_CAP) cnt = TIE_CAP;
        if (i < cnt) {
            int e = tie_list[i];
            int p1 = atomicAdd(&cursor2[tie_row[i]], 1); tcsr[p1] = e;
            int p2 = atomicAdd(&cursor2[tie_col[i]], 1); tcsr[p2] = e;
        }
    }
}

// ---------------- launch ----------------
extern "C" void kernel_launch(void* const* d_in, const int* in_sizes, int n_in,
                              void* d_out, int out_size, void* d_ws, size_t ws_size,
                              hipStream_t stream)
{
    const float* h     = (const float*)d_in[0];
    const float* e     = (const float*)d_in[1];
    const float* attr  = (const float*)d_in[2];
    const float* W_er1 = (const float*)d_in[3];
    const float* b_er1 = (const float*)d_in[4];
    const float* W_er2 = (const float*)d_in[5];
    const float* b_er2 = (const float*)d_in[6];
    const float* W_ih  = (const float*)d_in[7];
    const float* W_hh  = (const float*)d_in[8];
    const float* b_ih  = (const float*)d_in[9];
    const float* b_hh  = (const float*)d_in[10];
    const float* W_nn  = (const float*)d_in[11];
    const float* b_nn  = (const float*)d_in[12];
    const float* W_g1  = (const float*)d_in[13];
    const float* b_g1  = (const float*)d_in[14];
    const float* W_g2  = (const float*)d_in[15];
    const float* b_g2  = (const float*)d_in[16];
    const int*   ei    = (const int*)d_in[17];
    const void*  tie_raw = d_in[18];

    float* out_h = (float*)d_out;
    float* out_e = out_h + (size_t)N_NODES * HDIM;

    char* ws = (char*)d_ws;
    size_t off = 0;
    auto alloc = [&](size_t bytes) -> void* {
        void* p = ws + off;
        off = (off + bytes + 255) & ~(size_t)255;
        return p;
    };
    float* cpl_cnt = (float*)alloc((size_t)N_NODES * 4);
    float* w_den   = (float*)alloc((size_t)N_NODES * 4);
    int*   hist    = (int*)  alloc((size_t)N_NODES * 4);
    int*   counters= (int*)  alloc(256);  // [0]=fmt [1]=tie [2]=csr [3]=tcsr [4]=ncpl
    float* deg_inv = (float*)alloc((size_t)N_NODES * 4);
    float* sumw    = (float*)alloc((size_t)N_NODES * 4);
    float* w_arr   = (float*)alloc((size_t)N_EDGES * 4);
    int* tie_list  = (int*)alloc((size_t)TIE_CAP * 4);
    int* tie_row   = (int*)alloc((size_t)TIE_CAP * 4);
    int* tie_col   = (int*)alloc((size_t)TIE_CAP * 4);
    short* BTer1   = (short*)alloc((size_t)256 * 384 * 2);
    short* BTer2   = (short*)alloc((size_t)128 * 256 * 2);
    short* BTnn    = (short*)alloc((size_t)128 * 128 * 2);
    short* BTg1    = (short*)alloc((size_t)128 * 384 * 2);
    short* BTcomb  = (short*)alloc((size_t)256 * 256 * 2);
    short* BTihn   = (short*)alloc((size_t)128 * 128 * 2);
    short* BThhn   = (short*)alloc((size_t)128 * 128 * 2);
    uint16_t* h_bf = (uint16_t*)alloc((size_t)N_NODES * HDIM * 2);
    uint16_t* agg  = (uint16_t*)alloc((size_t)N_NODES * HDIM * 2);
    uint16_t* m_edge_bf = (uint16_t*)alloc((size_t)N_NODES * HDIM * 2);
    int* excl      = (int*)alloc((size_t)N_NODES * 4);
    int* excl2     = (int*)alloc((size_t)N_NODES * 4);
    int* bsum      = (int*)alloc(256 * 4);
    int* bsum2     = (int*)alloc(256 * 4);
    int* row_ptr   = (int*)alloc((size_t)(N_NODES + 1) * 4);
    int* row_ptr2  = (int*)alloc((size_t)(N_NODES + 1) * 4);
    int* cursor    = (int*)alloc((size_t)N_NODES * 4);
    int* cursor2   = (int*)alloc((size_t)N_NODES * 4);
    int* csr_row   = (int*)alloc((size_t)N_EDGES * 4);
    float* csr_w   = (float*)alloc((size_t)N_EDGES * 4);
    int* tcsr      = (int*)alloc((size_t)2 * TIE_CAP * 4);
    int* cpl_list  = (int*)alloc((size_t)N_NODES * 4);
    if (off > ws_size) return;

    const int GM_T = (TIE_CAP + BM_T - 1) / BM_T;    // 230
    const int GM_N = (N_NODES + BM_N - 1) / BM_N;    // 313 (upper bound)
    const int NB   = (N_NODES + SCAN_B - 1) / SCAN_B;

    k_init<<<INIT_BLOCKS, 256, 0, stream>>>(
        e, out_e, h, out_h, h_bf, cpl_cnt, w_den, hist, counters,
        (const uint8_t*)tie_raw,
        W_er1, W_er2, W_nn, W_g1, W_ih, W_hh,
        BTer1, BTer2, BTnn, BTg1, BTcomb, BTihn, BThhn);
    k_tie<<<EB_CONST, 256, 0, stream>>>(tie_raw, counters, ei, cpl_cnt,
                                        counters + 1, tie_list, tie_row, tie_col);
    k_w<<<EB_CONST, 256, 0, stream>>>(tie_raw, counters, ei, attr, cpl_cnt,
                                      w_den, w_arr, hist);
    k_scan1<<<NB, SCAN_B, 0, stream>>>(hist, cpl_cnt, excl, bsum, excl2, bsum2);
    k_scan2<<<1, 64, 0, stream>>>(bsum, bsum2, counters);
    k_scan3<<<(N_NODES + 256) / 256, 256, 0, stream>>>(
        excl, bsum, excl2, bsum2, row_ptr, cursor, row_ptr2, cursor2,
        counters, cpl_cnt, w_den, deg_inv, sumw, cpl_list);
    k_fill<<<EB_CONST + TB_CONST, 256, 0, stream>>>(
        ei, w_arr, w_den, cursor, csr_row, csr_w,
        counters, tie_list, tie_row, tie_col, cursor2, tcsr);

    for (int it = 0; it < NITER; ++it) {
        const float* e_src = (it == 0) ? e : out_e;
        k_tie_fused<<<GM_T, 512, 0, stream>>>(
            e_src, out_e, counters, h_bf, tie_list, tie_row, tie_col,
            BTer1, BTer2, b_er1, b_er2);
        k_gather<<<(N_NODES + 3) / 4, 256, 0, stream>>>(
            cpl_list, counters, row_ptr, csr_row, csr_w, h_bf, agg,
            row_ptr2, tcsr, out_e, deg_inv, m_edge_bf);
        k_node_mega<<<GM_N, 512, 0, stream>>>(
            cpl_list, counters, m_edge_bf, agg, out_h, h_bf, sumw,
            BTnn, b_nn, BTg1, b_g1, W_g2, b_g2,
            BTcomb, BTihn, BThhn, b_ih, b_hh);
    }
}